// Round 9
// baseline (20827.872 us; speedup 1.0000x reference)
//
#include <hip/hip_runtime.h>

// ---------------------------------------------------------------------------
// DeepMemoryLevel (ATLAS-style). B=2 S=1024 D=2048 M=512 P=1024 H=2048
// CHUNK=32 NC=32, tokens N=2048.
// Round 9: LDS-free 1-wave 64x64 MFMA GEMM (mgd_k) — MFMA fragments loaded
// directly from row-major global (16B/lane contiguous), double-buffered in
// registers. For 1-wave blocks LDS gave no sharing, only DS-unit serial cost.
// TA=1 (K=64 outer-product GEMMs) keep the old LDS kernel. No split-K.
// ---------------------------------------------------------------------------

typedef unsigned short us;
typedef __attribute__((ext_vector_type(8))) short s16x8;
typedef __attribute__((ext_vector_type(8))) unsigned short u16x8;
typedef __attribute__((ext_vector_type(4))) float f32x4;

#define MKP 72

__device__ __forceinline__ float gelu_f(float x) {
  return 0.5f * x * (1.0f + erff(x * 0.70710678118654752f));
}
__device__ __forceinline__ float gelu_grad_f(float x) {
  float cdf = 0.5f * (1.0f + erff(x * 0.70710678118654752f));
  float pdf = 0.3989422804014327f * expf(-0.5f * x * x);
  return cdf + x * pdf;
}
__device__ __forceinline__ float sigmoid_f(float x) { return 1.0f / (1.0f + expf(-x)); }

__device__ __forceinline__ us f2bf(float f) {
  union { float f; unsigned u; } v; v.f = f;
  unsigned r = (v.u + 0x7FFFu + ((v.u >> 16) & 1u)) >> 16;
  return (us)r;
}
__device__ __forceinline__ float bf2f(us h) {
  union { unsigned u; float f; } v; v.u = ((unsigned)h) << 16;
  return v.f;
}
// token-major index n -> chunk-major row
__device__ __forceinline__ int cm_map(int n) {
  return ((n & 1023) >> 5) * 64 + (n >> 10) * 32 + (n & 31);
}

__device__ __forceinline__ float block_reduce_sum(float v, float* red) {
  int t = threadIdx.x;
  red[t] = v; __syncthreads();
  for (int s = blockDim.x >> 1; s > 0; s >>= 1) {
    if (t < s) red[t] += red[t + s];
    __syncthreads();
  }
  float r = red[0];
  __syncthreads();
  return r;
}

// ---------------- epilogue (shared by both GEMM kernels) ----------------
// EPI: 5  C us = acc
//      6  C us = c1*acc + c2*bf(E_us[m,n])           (batched NS)
//      7  C f32 = acc
//      8  C us = gelu(acc); if m0>=64: C2 f32[(m-64),n] = gelu'(acc)
//      9  C us: m0<64 -> acc ; else -> 2*(acc - E_f32[(m-64),n])
//      13 C f32 = acc * E_f32[m,n]
//      14 C f32 = cp[3ci+1]*C_old - cp[3ci]*acc
//      15 C f32 = FX[m,n] + acc*OG[m]
//      17 C f32, row scattered to cm_map(m)
template<int EPI>
__device__ __forceinline__ void epilogue(f32x4 (&acc)[4][4], int m0, int n0,
    int l15, int l4, int bz, void* Cq, void* C2, const void* Eq,
    const float* FX, const float* OG, const float* cp, int cidx,
    int ldc, int lde, float c1, float c2, long sC, long sE) {
#pragma unroll
  for (int mi = 0; mi < 4; ++mi) {
#pragma unroll
    for (int i = 0; i < 4; ++i) {
      int grow = m0 + mi * 16 + l4 * 4 + i;
#pragma unroll
      for (int ni = 0; ni < 4; ++ni) {
        int col = n0 + ni * 16 + l15;
        float v = acc[mi][ni][i];
        if constexpr (EPI == 5) {
          ((us*)Cq + bz * sC)[(size_t)grow * ldc + col] = f2bf(v);
        } else if constexpr (EPI == 6) {
          const us* E = (const us*)Eq + bz * sE;
          ((us*)Cq + bz * sC)[(size_t)grow * ldc + col] =
              f2bf(c1 * v + c2 * bf2f(E[(size_t)grow * lde + col]));
        } else if constexpr (EPI == 7) {
          ((float*)Cq)[(size_t)grow * ldc + col] = v;
        } else if constexpr (EPI == 8) {
          ((us*)Cq)[(size_t)grow * ldc + col] = f2bf(gelu_f(v));
          if (m0 >= 64)
            ((float*)C2)[(size_t)(grow - 64) * ldc + col] = gelu_grad_f(v);
        } else if constexpr (EPI == 9) {
          if (m0 < 64)
            ((us*)Cq)[(size_t)grow * ldc + col] = f2bf(v);
          else
            ((us*)Cq)[(size_t)grow * ldc + col] =
                f2bf(2.0f * (v - ((const float*)Eq)[(size_t)(grow - 64) * lde + col]));
        } else if constexpr (EPI == 13) {
          ((float*)Cq)[(size_t)grow * ldc + col] =
              v * ((const float*)Eq)[(size_t)grow * lde + col];
        } else if constexpr (EPI == 14) {
          float* C = (float*)Cq;
          float old = C[(size_t)grow * ldc + col];
          C[(size_t)grow * ldc + col] = cp[cidx * 3 + 1] * old - cp[cidx * 3 + 0] * v;
        } else if constexpr (EPI == 15) {
          ((float*)Cq)[(size_t)grow * ldc + col] =
              FX[(size_t)grow * ldc + col] + v * OG[grow];
        } else if constexpr (EPI == 17) {
          int crow = cm_map(grow);
          ((float*)Cq)[(size_t)crow * ldc + col] = v;
        }
      }
    }
  }
}

// ---------------- LDS-free 1-wave 64x64 bf16 MFMA GEMM ----------------
// C[M,N] = A @ Bsrc^T ; A row-major M x K (lda), Bsrc row-major N x K (ldb).
// Fragments loaded directly global->reg (lane l: row base + l&15 rows,
// 16B at k + (l>>4)*8). Two register buffers (k, k+32); next pair's loads
// issued between MFMA phases. DUAL: rows [64,128) from A2. AG: row=cm_map.
template<int EPI, int DUAL, int AG>
__global__ __launch_bounds__(64)
void mgd_k(const us* __restrict__ Aq, const us* __restrict__ A2,
           const us* __restrict__ Bq, void* __restrict__ Cq,
           void* __restrict__ C2, const void* __restrict__ Eq,
           const float* __restrict__ FX, const float* __restrict__ OG,
           const float* __restrict__ cp, int cidx,
           int M, int N, int K, int lda, int ldb, int ldc, int lde,
           float c1, float c2, long sA, long sB, long sC, long sE) {
  const int bz = blockIdx.z;
  const us* A = Aq + (size_t)bz * sA;
  const us* B = Bq + (size_t)bz * sB;
  const int t = threadIdx.x;
  const int m0 = blockIdx.y * 64, n0 = blockIdx.x * 64;
  if constexpr (DUAL) { if (m0 >= 64) A = A2; }
  const int mA0 = DUAL ? (m0 & 63) : m0;
  const int l15 = t & 15, l4 = t >> 4;
  const int kof = l4 * 8;

  const us* arow[4];
  const us* brow[4];
#pragma unroll
  for (int mi = 0; mi < 4; ++mi) {
    int rowA = mA0 + mi * 16 + l15;
    if constexpr (AG) rowA = cm_map(m0 + mi * 16 + l15);
    arow[mi] = A + (size_t)rowA * lda + kof;
    brow[mi] = B + (size_t)(n0 + mi * 16 + l15) * ldb + kof;
  }

  f32x4 acc[4][4];
#pragma unroll
  for (int i = 0; i < 4; ++i)
#pragma unroll
    for (int j = 0; j < 4; ++j) acc[i][j] = (f32x4){0.f, 0.f, 0.f, 0.f};

  u16x8 a0[4], b0[4], a1[4], b1[4];
#pragma unroll
  for (int q = 0; q < 4; ++q) {
    a0[q] = *(const u16x8*)(arow[q] + 0);
    b0[q] = *(const u16x8*)(brow[q] + 0);
    a1[q] = *(const u16x8*)(arow[q] + 32);
    b1[q] = *(const u16x8*)(brow[q] + 32);
  }

  for (int k0 = 0; k0 < K; k0 += 64) {
#pragma unroll
    for (int mi = 0; mi < 4; ++mi)
#pragma unroll
      for (int ni = 0; ni < 4; ++ni)
        acc[mi][ni] = __builtin_amdgcn_mfma_f32_16x16x32_bf16(
            (s16x8)a0[mi], (s16x8)b0[ni], acc[mi][ni], 0, 0, 0);
    if (k0 + 64 < K) {
#pragma unroll
      for (int q = 0; q < 4; ++q) {
        a0[q] = *(const u16x8*)(arow[q] + k0 + 64);
        b0[q] = *(const u16x8*)(brow[q] + k0 + 64);
      }
    }
#pragma unroll
    for (int mi = 0; mi < 4; ++mi)
#pragma unroll
      for (int ni = 0; ni < 4; ++ni)
        acc[mi][ni] = __builtin_amdgcn_mfma_f32_16x16x32_bf16(
            (s16x8)a1[mi], (s16x8)b1[ni], acc[mi][ni], 0, 0, 0);
    if (k0 + 64 < K) {
#pragma unroll
      for (int q = 0; q < 4; ++q) {
        a1[q] = *(const u16x8*)(arow[q] + k0 + 96);
        b1[q] = *(const u16x8*)(brow[q] + k0 + 96);
      }
    }
  }

  epilogue<EPI>(acc, m0, n0, l15, l4, bz, Cq, C2, Eq, FX, OG, cp, cidx,
                ldc, lde, c1, c2, sC, sE);
}

template<int EPI, int DUAL = 0, int AG = 0>
static void mgd(hipStream_t st, const us* A, const us* A2, const us* B,
                void* C, void* C2, const void* E,
                const float* FX, const float* OG, const float* cp, int cidx,
                int M, int N, int K, int lda, int ldb, int ldc, int lde,
                float c1, float c2, long sA, long sB, long sC, long sE, int batch) {
  dim3 g(N / 64, M / 64, batch), b(64);
  hipLaunchKernelGGL((mgd_k<EPI, DUAL, AG>), g, b, 0, st, A, A2, B, C, C2, E,
                     FX, OG, cp, cidx, M, N, K, lda, ldb, ldc, lde, c1, c2, sA, sB, sC, sE);
}

// ---------------- LDS 1-wave 64x64 GEMM, TA=1 only (K=64 outer products) ----
// A row-major K x M (lda = M-stride). Barrier-free (single wave).
template<int EPI>
__global__ __launch_bounds__(64)
void mgt_k(const us* __restrict__ Aq, const us* __restrict__ Bq,
           void* __restrict__ Cq, const float* __restrict__ cp, int cidx,
           int M, int N, int K, int lda, int ldb, int ldc) {
  __shared__ __align__(16) us As[64 * MKP];
  __shared__ __align__(16) us Bs[64 * MKP];
  const us* A = Aq;
  const us* B = Bq;
  const int t = threadIdx.x;
  const int m0 = blockIdx.y * 64, n0 = blockIdx.x * 64;
  const int l15 = t & 15, l4 = t >> 4;

  f32x4 acc[4][4];
#pragma unroll
  for (int i = 0; i < 4; ++i)
#pragma unroll
    for (int j = 0; j < 4; ++j) acc[i][j] = (f32x4){0.f, 0.f, 0.f, 0.f};

  const int srw = t >> 3;
  const int sck = (t & 7) * 8;

  for (int k0 = 0; k0 < K; k0 += 64) {
#pragma unroll
    for (int p = 0; p < 8; ++p) {
      int kk = srw + p * 8;
      u16x8 v = *(const u16x8*)(A + (size_t)(k0 + kk) * lda + m0 + sck);
#pragma unroll
      for (int j = 0; j < 8; ++j) As[(sck + j) * MKP + kk] = v[j];
    }
#pragma unroll
    for (int p = 0; p < 8; ++p) {
      int row = srw + p * 8;
      u16x8 v = *(const u16x8*)(B + (size_t)(n0 + row) * ldb + k0 + sck);
      *(u16x8*)&Bs[row * MKP + sck] = v;
    }
#pragma unroll
    for (int ks = 0; ks < 2; ++ks) {
      s16x8 af[4], bf[4];
#pragma unroll
      for (int mi = 0; mi < 4; ++mi)
        af[mi] = *(const s16x8*)&As[(mi * 16 + l15) * MKP + ks * 32 + l4 * 8];
#pragma unroll
      for (int ni = 0; ni < 4; ++ni)
        bf[ni] = *(const s16x8*)&Bs[(ni * 16 + l15) * MKP + ks * 32 + l4 * 8];
#pragma unroll
      for (int mi = 0; mi < 4; ++mi)
#pragma unroll
        for (int ni = 0; ni < 4; ++ni)
          acc[mi][ni] = __builtin_amdgcn_mfma_f32_16x16x32_bf16(af[mi], bf[ni], acc[mi][ni], 0, 0, 0);
    }
  }

  epilogue<EPI>(acc, m0, n0, l15, l4, 0, Cq, nullptr, nullptr, nullptr, nullptr,
                cp, cidx, ldc, 0, 0.f, 0.f, 0, 0);
}

template<int EPI>
static void mgt(hipStream_t st, const us* A, const us* B, void* C,
                const float* cp, int cidx, int M, int N, int K,
                int lda, int ldb, int ldc) {
  dim3 g(N / 64, M / 64, 1), b(64);
  hipLaunchKernelGGL((mgt_k<EPI>), g, b, 0, st, A, B, C, cp, cidx,
                     M, N, K, lda, ldb, ldc);
}

// ---------------- conversions ----------------

__global__ __launch_bounds__(256) void conv_k(const float* __restrict__ in,
                                              us* __restrict__ out, int n) {
  for (int i = blockIdx.x * 256 + threadIdx.x; i < n; i += gridDim.x * 256)
    out[i] = f2bf(in[i]);
}

__global__ void tconv_k(const float* __restrict__ in, us* __restrict__ out, int R, int C) {
  __shared__ float tile[32][33];
  int c0 = blockIdx.x * 32, r0 = blockIdx.y * 32;
  int tx = threadIdx.x, ty = threadIdx.y;
#pragma unroll
  for (int j = 0; j < 4; ++j)
    tile[ty + 8 * j][tx] = in[(size_t)(r0 + ty + 8 * j) * C + c0 + tx];
  __syncthreads();
#pragma unroll
  for (int j = 0; j < 4; ++j)
    out[(size_t)(c0 + ty + 8 * j) * R + r0 + tx] = f2bf(tile[tx][ty + 8 * j]);
}

// ---------------- elementwise / reductions ----------------

__global__ __launch_bounds__(256) void polynorm2_k(const float* __restrict__ lin,
                                                   us* __restrict__ outp) {
  __shared__ float red[256];
  int n = blockIdx.x, t = threadIdx.x;
  int rowp = cm_map(n);
  float s = 0.f;
  for (int f = t; f < 512; f += 256) { float v = lin[(size_t)n * 512 + f]; s += v * v; }
  float tot = block_reduce_sum(s, red);
  float sc = 1.0f / fmaxf(sqrtf(tot), 1e-12f);
  const float is2 = 0.70710678118654752f;
  for (int f = t; f < 512; f += 256) {
    float v = lin[(size_t)n * 512 + f] * sc;
    outp[(size_t)rowp * 1024 + f] = f2bf(v * is2);
    outp[(size_t)rowp * 1024 + 512 + f] = f2bf(v * v * is2);
  }
}

__global__ __launch_bounds__(256) void gates_k(const float* __restrict__ x,
    const float* __restrict__ wlr, const float* __restrict__ blr,
    const float* __restrict__ wmom, const float* __restrict__ bmom,
    const float* __restrict__ wdec, const float* __restrict__ bdec,
    const float* __restrict__ wgate, const float* __restrict__ bgate,
    float* __restrict__ lrv, float* __restrict__ momv,
    float* __restrict__ decv, float* __restrict__ og) {
  __shared__ float red[256];
  int n = blockIdx.x, t = threadIdx.x;
  float s0 = 0.f, s1 = 0.f, s2 = 0.f, s3 = 0.f;
  for (int d = t; d < 2048; d += 256) {
    float xv = x[(size_t)n * 2048 + d];
    s0 += xv * wlr[d]; s1 += xv * wmom[d]; s2 += xv * wdec[d]; s3 += xv * wgate[d];
  }
  float r0 = block_reduce_sum(s0, red);
  float r1 = block_reduce_sum(s1, red);
  float r2 = block_reduce_sum(s2, red);
  float r3 = block_reduce_sum(s3, red);
  if (t == 0) {
    lrv[n] = sigmoid_f(r0 + blr[0]);
    momv[n] = sigmoid_f(r1 + bmom[0]);
    decv[n] = sigmoid_f(r2 + bdec[0]);
    og[n] = sigmoid_f(r3 + bgate[0]);
  }
}

__global__ void chunk_means_k(const float* __restrict__ lrv, const float* __restrict__ momv,
                              const float* __restrict__ decv, float* __restrict__ cp) {
  int c = blockIdx.x, t = threadIdx.x;  // 64 threads
  int n = ((t >> 5) << 10) + c * 32 + (t & 31);
  float a = lrv[n], b = momv[n], d = decv[n];
  for (int off = 32; off > 0; off >>= 1) {
    a += __shfl_down(a, off);
    b += __shfl_down(b, off);
    d += __shfl_down(d, off);
  }
  if (t == 0) {
    cp[c * 3 + 0] = a * (1.f / 64.f);
    cp[c * 3 + 1] = b * (1.f / 64.f);
    cp[c * 3 + 2] = d * (1.f / 64.f);
  }
}

__global__ __launch_bounds__(256) void sampnorm2_k(const us* __restrict__ kp_b,
                                                   const float* __restrict__ dh,
                                                   const us* __restrict__ hab,
                                                   const us* __restrict__ pr,
                                                   float* __restrict__ w0inv,
                                                   float* __restrict__ w1inv, int c) {
  __shared__ float red[256];
  int i = blockIdx.x, t = threadIdx.x;
  int row = c * 64 + i;
  float sk = 0.f, sr = 0.f, sdh = 0.f, sa = 0.f;
  for (int p = t; p < 1024; p += 256) {
    float v = bf2f(kp_b[(size_t)row * 1024 + p]); sk += v * v;
    v = bf2f(pr[(size_t)(64 + i) * 1024 + p]); sr += v * v;
  }
  for (int h = t; h < 2048; h += 256) {
    float v = dh[(size_t)i * 2048 + h]; sdh += v * v;
    v = bf2f(hab[(size_t)(64 + i) * 2048 + h]); sa += v * v;
  }
  float tk = block_reduce_sum(sk, red);
  float tdh = block_reduce_sum(sdh, red);
  float ta = block_reduce_sum(sa, red);
  float tr = block_reduce_sum(sr, red);
  if (t == 0) {
    float n0 = fmaxf(sqrtf(tk) * sqrtf(tdh), 1e-8f);
    w0inv[i] = 1.0f / (64.0f * fmaxf(n0 * 0.1f, 1.0f));
    float n1 = fmaxf(sqrtf(ta) * sqrtf(tr), 1e-8f);
    w1inv[i] = 1.0f / (64.0f * fmaxf(n1 * 0.1f, 1.0f));
  }
}

template<int INF32>
__global__ void wtrans_k(const void* __restrict__ in, const float* __restrict__ w,
                         us* __restrict__ out, int C, int ldin) {
  __shared__ float tile[32][33];
  int c0 = blockIdx.x * 32, r0 = blockIdx.y * 32;
  int tx = threadIdx.x, ty = threadIdx.y;
#pragma unroll
  for (int j = 0; j < 4; ++j) {
    int r = r0 + ty + 8 * j, cc = c0 + tx;
    float v;
    if constexpr (INF32) v = ((const float*)in)[(size_t)r * ldin + cc];
    else v = bf2f(((const us*)in)[(size_t)r * ldin + cc]);
    tile[ty + 8 * j][tx] = v * w[r];
  }
  __syncthreads();
#pragma unroll
  for (int j = 0; j < 4; ++j)
    out[(size_t)(c0 + ty + 8 * j) * 64 + r0 + tx] = f2bf(tile[tx][ty + 8 * j]);
}

__global__ __launch_bounds__(256) void frob2_k(const float* __restrict__ s0,
                                               const float* __restrict__ s1, int n,
                                               float* __restrict__ parts) {
  __shared__ float red[256];
  const float* s = blockIdx.z ? s1 : s0;
  float acc = 0.f;
  for (int i = blockIdx.x * 256 + threadIdx.x; i < n; i += gridDim.x * 256) {
    float v = s[i]; acc += v * v;
  }
  float r = block_reduce_sum(acc, red);
  if (threadIdx.x == 0) parts[blockIdx.z * 256 + blockIdx.x] = r;
}

__global__ __launch_bounds__(256) void frob_fin2_k(const float* __restrict__ parts,
                                                   float* __restrict__ inv) {
  __shared__ float red[256];
  float r = block_reduce_sum(parts[blockIdx.x * 256 + threadIdx.x], red);
  if (threadIdx.x == 0) inv[blockIdx.x] = 1.0f / (sqrtf(r) + 1e-7f);
}

__global__ void scale_dual_k(const float* __restrict__ in, us* __restrict__ outS,
                             us* __restrict__ outT, const float* __restrict__ inv,
                             int R, int C) {
  __shared__ float tile[32][33];
  float s = *inv;
  int c0 = blockIdx.x * 32, r0 = blockIdx.y * 32;
  int tx = threadIdx.x, ty = threadIdx.y;
#pragma unroll
  for (int j = 0; j < 4; ++j) {
    float v = in[(size_t)(r0 + ty + 8 * j) * C + c0 + tx];
    tile[ty + 8 * j][tx] = v;
    outS[(size_t)(r0 + ty + 8 * j) * C + c0 + tx] = f2bf(v * s);
  }
  __syncthreads();
#pragma unroll
  for (int j = 0; j < 4; ++j)
    outT[(size_t)(c0 + ty + 8 * j) * R + r0 + tx] = f2bf(tile[tx][ty + 8 * j] * s);
}

__global__ void tbf_k(const us* __restrict__ in, us* __restrict__ out) {
  __shared__ us tile[32][33];
  size_t bo = (size_t)blockIdx.z * 2097152;
  int c0 = blockIdx.x * 32, r0 = blockIdx.y * 32;
  int tx = threadIdx.x, ty = threadIdx.y;
#pragma unroll
  for (int j = 0; j < 4; ++j)
    tile[ty + 8 * j][tx] = in[bo + (size_t)(r0 + ty + 8 * j) * 2048 + c0 + tx];
  __syncthreads();
#pragma unroll
  for (int j = 0; j < 4; ++j)
    out[bo + (size_t)(c0 + ty + 8 * j) * 1024 + r0 + tx] = tile[tx][ty + 8 * j];
}

__global__ void wupd0_k(float* __restrict__ W0, const us* __restrict__ X,
                        us* __restrict__ W0bT, const float* __restrict__ cp, int c) {
  __shared__ float tl[32][33];
  float lr = cp[c * 3 + 0], om = 1.0f - cp[c * 3 + 2];
  int c0 = blockIdx.x * 32, r0 = blockIdx.y * 32;
  int tx = threadIdx.x, ty = threadIdx.y;
#pragma unroll
  for (int j = 0; j < 4; ++j) {
    int r = r0 + ty + 8 * j, h = c0 + tx;
    size_t idx = (size_t)r * 2048 + h;
    float v = om * W0[idx] + lr * bf2f(X[idx]);
    W0[idx] = v;
    tl[ty + 8 * j][tx] = v;
  }
  __syncthreads();
#pragma unroll
  for (int j = 0; j < 4; ++j)
    W0bT[(size_t)(c0 + ty + 8 * j) * 1024 + r0 + tx] = f2bf(tl[tx][ty + 8 * j]);
}

__global__ void wupd1_k(float* __restrict__ W1, const us* __restrict__ X2,
                        us* __restrict__ W1b, us* __restrict__ W1bT,
                        const float* __restrict__ cp, int c) {
  __shared__ float tX[32][33];
  __shared__ float t2[32][33];
  float lr = cp[c * 3 + 0], om = 1.0f - cp[c * 3 + 2];
  int h0 = blockIdx.x * 32, p0 = blockIdx.y * 32;
  int tx = threadIdx.x, ty = threadIdx.y;
#pragma unroll
  for (int j = 0; j < 4; ++j)
    tX[ty + 8 * j][tx] = bf2f(X2[(size_t)(p0 + ty + 8 * j) * 2048 + h0 + tx]);
  __syncthreads();
#pragma unroll
  for (int j = 0; j < 4; ++j) {
    int h = h0 + ty + 8 * j, p = p0 + tx;
    size_t idx = (size_t)h * 1024 + p;
    float v = om * W1[idx] + lr * tX[tx][ty + 8 * j];
    W1[idx] = v;
    W1b[idx] = f2bf(v);
    t2[tx][ty + 8 * j] = v;
  }
  __syncthreads();
#pragma unroll
  for (int j = 0; j < 4; ++j)
    W1bT[(size_t)(p0 + ty + 8 * j) * 2048 + h0 + tx] = f2bf(t2[ty + 8 * j][tx]);
}

// ---------------- host ----------------

extern "C" void kernel_launch(void* const* d_in, const int* in_sizes, int n_in,
                              void* d_out, int out_size, void* d_ws, size_t ws_size,
                              hipStream_t stream) {
  const float* x = (const float*)d_in[0];
  const float* Wk = (const float*)d_in[1];
  const float* Wv = (const float*)d_in[2];
  const float* Wq = (const float*)d_in[3];
  const float* Wout = (const float*)d_in[4];
  const float* w_lr = (const float*)d_in[5];
  const float* b_lr = (const float*)d_in[6];
  const float* w_mom = (const float*)d_in[7];
  const float* b_mom = (const float*)d_in[8];
  const float* w_dec = (const float*)d_in[9];
  const float* b_dec = (const float*)d_in[10];
  const float* w_gate = (const float*)d_in[11];
  const float* b_gate = (const float*)d_in[12];
  const float* Wmem0 = (const float*)d_in[13];
  const float* Wmem1 = (const float*)d_in[14];
  const float* Wmemout = (const float*)d_in[15];
  const float* Wvexp = (const float*)d_in[16];
  float* out = (float*)d_out;
  (void)n_in; (void)in_sizes; (void)out_size;

  const long F = 1048576;
  const long BIG = 2097152;
  const long SB2 = 2097152, SB1 = 1048576;
  float* ws = (float*)d_ws;
  if (ws_size < (size_t)25043464 * sizeof(float)) return;

  us* kp_b   = (us*)ws;               // [0,1F)
  us* qp_b   = (us*)(ws + F);         // [1,2)
  float* vexp = ws + 2 * F;           // [2,4)
  float* W0  = ws + 4 * F;            // [4,6)
  float* W1  = ws + 6 * F;            // [6,8)
  float* S0  = ws + 8 * F;            // [8,10)
  float* S1  = ws + 10 * F;           // [10,12)
  us* XA     = (us*)(ws + 12 * F);    // [12,14)
  us* XB     = (us*)(ws + 14 * F);    // [14,16)
  us* XT     = (us*)(ws + 16 * F);    // [16,18)
  us* Ab     = (us*)(ws + 18 * F);    // [18,19)
  float* SCR = ws + 19 * F;           // [19,20)
  us* W0bT   = (us*)(ws + 20 * F);    // [20,21)
  us* W1bT   = (us*)(ws + 21 * F);    // [21,22)
  us* W1b    = (us*)(ws + 22 * F);    // [22,23)
  us* WmoT   = (us*)(ws + 23 * F);    // [23,23.25)
  us* retrv  = (us*)(ws + 23 * F + 262144);
  float* smal = ws + 23 * F + 262144 + 524288;
  float* og   = smal;
  float* lrv  = og + 2048;
  float* momv = lrv + 2048;
  float* decv = momv + 2048;
  float* cpb  = decv + 2048;
  float* w0inv = cpb + 128;
  float* w1inv = w0inv + 64;
  float* parts = w1inv + 64;
  float* inv01 = parts + 512;

  us* xb   = XA;
  us* Wkb  = XB;
  us* Wqb  = XB + 1048576;
  us* Wvb  = XB + 2097152;
  us* vlin = XT;
  us* WvexpT = XT + 1048576;
  us* Woutb = Ab;
  float* lin = SCR;
  us* Bb = (us*)SCR;
  us* hab   = (us*)SCR;
  float* gp = SCR + 131072;
  us* pr    = (us*)(SCR + 262144);
  float* dh = SCR + 327680;
  us* dhT   = (us*)(SCR + 458752);
  us* rbwT  = (us*)(SCR + 524288);

  const float NSa = 3.4445f, NSb = -4.7750f, NSc = 2.0315f;

  hipMemcpyAsync(W0, Wmem0, (size_t)BIG * 4, hipMemcpyDeviceToDevice, stream);
  hipMemcpyAsync(W1, Wmem1, (size_t)BIG * 4, hipMemcpyDeviceToDevice, stream);
  hipMemsetAsync(S0, 0, (size_t)BIG * 4, stream);
  hipMemsetAsync(S1, 0, (size_t)BIG * 4, stream);
  hipLaunchKernelGGL(tconv_k, dim3(64, 32), dim3(32, 8), 0, stream, Wmem0, W0bT, 1024, 2048);
  hipLaunchKernelGGL(conv_k, dim3(1024), dim3(256), 0, stream, Wmem1, W1b, (int)BIG);
  hipLaunchKernelGGL(tconv_k, dim3(32, 64), dim3(32, 8), 0, stream, Wmem1, W1bT, 2048, 1024);
  hipLaunchKernelGGL(tconv_k, dim3(16, 32), dim3(32, 8), 0, stream, Wmemout, WmoT, 1024, 512);
  hipLaunchKernelGGL(tconv_k, dim3(32, 16), dim3(32, 8), 0, stream, Wvexp, WvexpT, 512, 1024);
  hipLaunchKernelGGL(conv_k, dim3(2048), dim3(256), 0, stream, x, xb, 2048 * 2048);
  hipLaunchKernelGGL(conv_k, dim3(512), dim3(256), 0, stream, Wk, Wkb, 512 * 2048);
  hipLaunchKernelGGL(conv_k, dim3(512), dim3(256), 0, stream, Wq, Wqb, 512 * 2048);
  hipLaunchKernelGGL(conv_k, dim3(512), dim3(256), 0, stream, Wv, Wvb, 512 * 2048);

  mgd<7>(stream, xb, nullptr, Wkb, lin, nullptr, nullptr, nullptr, nullptr, nullptr, 0,
         2048, 512, 2048, 2048, 2048, 512, 0, 0.f, 0.f, 0, 0, 0, 0, 1);
  hipLaunchKernelGGL(polynorm2_k, dim3(2048), dim3(256), 0, stream, lin, kp_b);
  mgd<7>(stream, xb, nullptr, Wqb, lin, nullptr, nullptr, nullptr, nullptr, nullptr, 0,
         2048, 512, 2048, 2048, 2048, 512, 0, 0.f, 0.f, 0, 0, 0, 0, 1);
  hipLaunchKernelGGL(polynorm2_k, dim3(2048), dim3(256), 0, stream, lin, qp_b);
  mgd<5>(stream, xb, nullptr, Wvb, vlin, nullptr, nullptr, nullptr, nullptr, nullptr, 0,
         2048, 512, 2048, 2048, 2048, 512, 0, 0.f, 0.f, 0, 0, 0, 0, 1);
  mgd<17>(stream, vlin, nullptr, WvexpT, vexp, nullptr, nullptr, nullptr, nullptr, nullptr, 0,
          2048, 1024, 512, 512, 512, 1024, 0, 0.f, 0.f, 0, 0, 0, 0, 1);

  hipLaunchKernelGGL(gates_k, dim3(2048), dim3(256), 0, stream, x,
                     w_lr, b_lr, w_mom, b_mom, w_dec, b_dec, w_gate, b_gate,
                     lrv, momv, decv, og);
  hipLaunchKernelGGL(chunk_means_k, dim3(32), dim3(64), 0, stream, lrv, momv, decv, cpb);

  for (int c = 0; c < 32; ++c) {
    const us* kp_c = kp_b + (size_t)c * 64 * 1024;
    const us* qp_c = qp_b + (size_t)c * 64 * 1024;
    const float* vexp_c = vexp + (size_t)c * 64 * 1024;
    mgd<8, 1>(stream, qp_c, kp_c, W0bT, hab, gp, nullptr, nullptr, nullptr, nullptr, 0,
              128, 2048, 1024, 1024, 1024, 2048, 0, 0.f, 0.f, 0, 0, 0, 0, 1);
    mgd<9>(stream, hab, nullptr, W1bT, pr, nullptr, vexp_c, nullptr, nullptr, nullptr, 0,
           128, 1024, 2048, 2048, 2048, 1024, 1024, 0.f, 0.f, 0, 0, 0, 0, 1);
    mgd<5>(stream, pr, nullptr, WmoT, retrv + (size_t)c * 64 * 512, nullptr, nullptr,
           nullptr, nullptr, nullptr, 0,
           64, 512, 1024, 1024, 1024, 512, 0, 0.f, 0.f, 0, 0, 0, 0, 1);
    mgd<13>(stream, pr + 64 * 1024, nullptr, W1b, dh, nullptr, gp, nullptr, nullptr, nullptr, 0,
            64, 2048, 1024, 1024, 1024, 2048, 2048, 0.f, 0.f, 0, 0, 0, 0, 1);
    hipLaunchKernelGGL(sampnorm2_k, dim3(64), dim3(256), 0, stream,
                       kp_b, dh, hab, pr, w0inv, w1inv, c);
    hipLaunchKernelGGL((wtrans_k<1>), dim3(64, 2), dim3(32, 8), 0, stream, dh, w0inv, dhT, 2048, 2048);
    hipLaunchKernelGGL((wtrans_k<0>), dim3(32, 2), dim3(32, 8), 0, stream, pr + 64 * 1024, w1inv,
                       rbwT, 1024, 1024);
    // G5: S0 = mom*S0 - lr*(kc^T dh_w)   (A = kp_c as K x M, K=64)
    mgt<14>(stream, kp_c, dhT, S0, cpb, c, 1024, 2048, 64, 1024, 64, 2048);
    // G6: S1 = mom*S1 - lr*(a^T r_w)
    mgt<14>(stream, hab + 64 * 2048, rbwT, S1, cpb, c, 2048, 1024, 64, 2048, 64, 1024);

    // ---- batched NS5: batch0 = S0 (1024x2048), batch1 = S1^T ----
    hipLaunchKernelGGL(frob2_k, dim3(256, 1, 2), dim3(256), 0, stream, S0, S1, (int)BIG, parts);
    hipLaunchKernelGGL(frob_fin2_k, dim3(2), dim3(256), 0, stream, parts, inv01);
    hipLaunchKernelGGL(scale_dual_k, dim3(64, 32), dim3(32, 8), 0, stream,
                       S0, XA, XT, inv01, 1024, 2048);
    hipLaunchKernelGGL(scale_dual_k, dim3(32, 64), dim3(32, 8), 0, stream,
                       S1, XT + SB2, XA + SB2, inv01 + 1, 2048, 1024);

    us* Xc = XA;
    us* Xn = XB;
    for (int it = 0; it < 5; ++it) {
      // Ab = Xc @ Xc^T
      mgd<5>(stream, Xc, nullptr, Xc, Ab, nullptr, nullptr, nullptr, nullptr, nullptr, 0,
             1024, 1024, 2048, 2048, 2048, 1024, 0, 0.f, 0.f, SB2, SB2, SB1, 0, 2);
      // Bb = NSc*(Ab@Ab) + NSb*Ab
      mgd<6>(stream, Ab, nullptr, Ab, Bb, nullptr, Ab, nullptr, nullptr, nullptr, 0,
             1024, 1024, 1024, 1024, 1024, 1024, 1024, NSc, NSb, SB1, SB1, SB1, SB1, 2);
      // Xn = Bb@Xc + NSa*Xc   (B operand = XT = Xc^T)
      mgd<6>(stream, Bb, nullptr, XT, Xn, nullptr, Xc, nullptr, nullptr, nullptr, 0,
             1024, 2048, 1024, 1024, 1024, 2048, 2048, 1.0f, NSa, SB1, SB2, SB2, SB2, 2);
      if (it < 4)
        hipLaunchKernelGGL(tbf_k, dim3(64, 32, 2), dim3(32, 8), 0, stream, Xn, XT);
      us* tmp = Xc; Xc = Xn; Xn = tmp;
    }
    hipLaunchKernelGGL(wupd0_k, dim3(64, 32), dim3(32, 8), 0, stream, W0, Xc, W0bT, cpb, c);
    hipLaunchKernelGGL(wupd1_k, dim3(64, 32), dim3(32, 8), 0, stream, W1, Xc + SB2, W1b, W1bT, cpb, c);
  }

  hipLaunchKernelGGL(conv_k, dim3(1024), dim3(256), 0, stream, Wout, Woutb, 2048 * 512);
  mgd<15, 0, 1>(stream, retrv, nullptr, Woutb, out, nullptr, nullptr, x, og, nullptr, 0,
                2048, 2048, 512, 512, 512, 2048, 0, 0.f, 0.f, 0, 0, 0, 0, 1);
}

// Round 11
// 17228.273 us; speedup vs baseline: 1.2089x; 1.2089x over previous
//
#include <hip/hip_runtime.h>

// ---------------------------------------------------------------------------
// DeepMemoryLevel (ATLAS-style). B=2 S=1024 D=2048 M=512 P=1024 H=2048
// CHUNK=32 NC=32, tokens N=2048.
// Round 10 (resubmit after infra failure): R7 base (barrier-free 1-wave 64x64
// LDS MFMA GEMM) + split-K=2 on the three NS5 GEMMs (grids 512->1024/1024/
// 2048 blocks = 4-8 waves/CU). bf16 partials in dead buffers; combA/combB/
// combX combines (combX folds the Xn-transpose, removing tbf).
// Chunk path identical to R7.
// ---------------------------------------------------------------------------

typedef unsigned short us;
typedef __attribute__((ext_vector_type(8))) short s16x8;
typedef __attribute__((ext_vector_type(8))) unsigned short u16x8;
typedef __attribute__((ext_vector_type(4))) float f32x4;

#define MKP 72

__device__ __forceinline__ float gelu_f(float x) {
  return 0.5f * x * (1.0f + erff(x * 0.70710678118654752f));
}
__device__ __forceinline__ float gelu_grad_f(float x) {
  float cdf = 0.5f * (1.0f + erff(x * 0.70710678118654752f));
  float pdf = 0.3989422804014327f * expf(-0.5f * x * x);
  return cdf + x * pdf;
}
__device__ __forceinline__ float sigmoid_f(float x) { return 1.0f / (1.0f + expf(-x)); }

__device__ __forceinline__ us f2bf(float f) {
  union { float f; unsigned u; } v; v.f = f;
  unsigned r = (v.u + 0x7FFFu + ((v.u >> 16) & 1u)) >> 16;
  return (us)r;
}
__device__ __forceinline__ float bf2f(us h) {
  union { unsigned u; float f; } v; v.u = ((unsigned)h) << 16;
  return v.f;
}
// token-major index n -> chunk-major row
__device__ __forceinline__ int cm_map(int n) {
  return ((n & 1023) >> 5) * 64 + (n >> 10) * 32 + (n & 31);
}

__device__ __forceinline__ float block_reduce_sum(float v, float* red) {
  int t = threadIdx.x;
  red[t] = v; __syncthreads();
  for (int s = blockDim.x >> 1; s > 0; s >>= 1) {
    if (t < s) red[t] += red[t + s];
    __syncthreads();
  }
  float r = red[0];
  __syncthreads();
  return r;
}

// ---------------- epilogue ----------------
// EPI: 5  C us = acc
//      6  C us = c1*acc + c2*bf(E_us[m,n])
//      7  C f32 = acc
//      8  C us = gelu(acc); if m0>=64: C2 f32[(m-64),n] = gelu'(acc)
//      9  C us: m0<64 -> acc ; else -> 2*(acc - E_f32[(m-64),n])
//      13 C f32 = acc * E_f32[m,n]
//      14 C f32 = cp[3ci+1]*C_old - cp[3ci]*acc
//      15 C f32 = FX[m,n] + acc*OG[m]
//      17 C f32, row scattered to cm_map(m)
template<int EPI>
__device__ __forceinline__ void epilogue(f32x4 (&acc)[4][4], int m0, int n0,
    int l15, int l4, void* Cq, void* C2, const void* Eq,
    const float* FX, const float* OG, const float* cp, int cidx,
    int ldc, int lde, float c1, float c2) {
#pragma unroll
  for (int mi = 0; mi < 4; ++mi) {
#pragma unroll
    for (int i = 0; i < 4; ++i) {
      int grow = m0 + mi * 16 + l4 * 4 + i;
#pragma unroll
      for (int ni = 0; ni < 4; ++ni) {
        int col = n0 + ni * 16 + l15;
        float v = acc[mi][ni][i];
        if constexpr (EPI == 5) {
          ((us*)Cq)[(size_t)grow * ldc + col] = f2bf(v);
        } else if constexpr (EPI == 6) {
          ((us*)Cq)[(size_t)grow * ldc + col] =
              f2bf(c1 * v + c2 * bf2f(((const us*)Eq)[(size_t)grow * lde + col]));
        } else if constexpr (EPI == 7) {
          ((float*)Cq)[(size_t)grow * ldc + col] = v;
        } else if constexpr (EPI == 8) {
          ((us*)Cq)[(size_t)grow * ldc + col] = f2bf(gelu_f(v));
          if (m0 >= 64)
            ((float*)C2)[(size_t)(grow - 64) * ldc + col] = gelu_grad_f(v);
        } else if constexpr (EPI == 9) {
          if (m0 < 64)
            ((us*)Cq)[(size_t)grow * ldc + col] = f2bf(v);
          else
            ((us*)Cq)[(size_t)grow * ldc + col] =
                f2bf(2.0f * (v - ((const float*)Eq)[(size_t)(grow - 64) * lde + col]));
        } else if constexpr (EPI == 13) {
          ((float*)Cq)[(size_t)grow * ldc + col] =
              v * ((const float*)Eq)[(size_t)grow * lde + col];
        } else if constexpr (EPI == 14) {
          float* C = (float*)Cq;
          float old = C[(size_t)grow * ldc + col];
          C[(size_t)grow * ldc + col] = cp[cidx * 3 + 1] * old - cp[cidx * 3 + 0] * v;
        } else if constexpr (EPI == 15) {
          ((float*)Cq)[(size_t)grow * ldc + col] =
              FX[(size_t)grow * ldc + col] + v * OG[grow];
        } else if constexpr (EPI == 17) {
          int crow = cm_map(grow);
          ((float*)Cq)[(size_t)crow * ldc + col] = v;
        }
      }
    }
  }
}

// ---------------- 1-wave 64x64 bf16 MFMA GEMM (barrier-free pipeline) -------
// C[M,N] = A @ Bsrc^T, Bsrc row-major N x K (ldb).
// TA=0: A row-major M x K (lda). TA=1: A row-major K x M (lda = M-stride).
// DUAL: block rows [64,128) read from A2. AG: global A row = cm_map.
// KS: split-K; grid.z = batch*KS; bz -> (bb=bz/KS, ss=bz%KS); block covers
// K-range [ss*K/KS,(ss+1)*K/KS). For EPI 5/6 the C partial for bz goes to
// Cq + bz*sC if bz < zthr, else C2 + (bz-zthr)*sC.
template<int EPI, int TA, int DUAL, int AG, int KS>
__global__ __launch_bounds__(64)
void mg_k(const us* __restrict__ Aq, const us* __restrict__ A2,
          const us* __restrict__ Bq, void* __restrict__ Cq,
          void* __restrict__ C2, const void* __restrict__ Eq,
          const float* __restrict__ FX, const float* __restrict__ OG,
          const float* __restrict__ cp, int cidx,
          int M, int N, int K, int lda, int ldb, int ldc, int lde,
          float c1, float c2, long sA, long sB, long sC, long sE, int zthr) {
  __shared__ __align__(16) us As[64 * MKP];
  __shared__ __align__(16) us Bs[64 * MKP];
  const int bz = blockIdx.z;
  const int bb = bz / KS, ss = bz % KS;
  const int KH = K / KS;
  const us* A = Aq + (size_t)bb * sA;
  if constexpr (TA == 0) A += (size_t)ss * KH;
  else A += (size_t)ss * KH * lda;
  const us* B = Bq + (size_t)bb * sB + (size_t)ss * KH;
  const int t = threadIdx.x;
  const int m0 = blockIdx.y * 64, n0 = blockIdx.x * 64;
  if constexpr (DUAL) { if (m0 >= 64) A = A2; }
  const int mA0 = DUAL ? (m0 & 63) : m0;
  const int l15 = t & 15, l4 = t >> 4;

  f32x4 acc[4][4];
#pragma unroll
  for (int i = 0; i < 4; ++i)
#pragma unroll
    for (int j = 0; j < 4; ++j) acc[i][j] = (f32x4){0.f, 0.f, 0.f, 0.f};

  const int srw = t >> 3;          // 0..7 base row / k
  const int sck = (t & 7) * 8;     // 0..56 col chunk

  u16x8 ra[8], rb[8];
  auto LDA = [&](int k0) {
#pragma unroll
    for (int p = 0; p < 8; ++p) {
      if constexpr (TA == 0) {
        int row = srw + p * 8;
        int srow;
        if constexpr (AG) srow = cm_map(m0 + row); else srow = mA0 + row;
        ra[p] = *(const u16x8*)(A + (size_t)srow * lda + k0 + sck);
      } else {
        ra[p] = *(const u16x8*)(A + (size_t)(k0 + srw + p * 8) * lda + mA0 + sck);
      }
    }
  };
  auto LDB = [&](int k0) {
#pragma unroll
    for (int p = 0; p < 8; ++p)
      rb[p] = *(const u16x8*)(B + (size_t)(n0 + srw + p * 8) * ldb + k0 + sck);
  };

  LDA(0); LDB(0);
  for (int k0 = 0; k0 < KH; k0 += 64) {
    // stage current regs -> LDS (per-wave DS in-order: no barrier needed)
    if constexpr (TA == 0) {
#pragma unroll
      for (int p = 0; p < 8; ++p)
        *(u16x8*)&As[(srw + p * 8) * MKP + sck] = ra[p];
    } else {
#pragma unroll
      for (int p = 0; p < 8; ++p) {
        int kk = srw + p * 8;
#pragma unroll
        for (int j = 0; j < 8; ++j) As[(sck + j) * MKP + kk] = ra[p][j];
      }
    }
#pragma unroll
    for (int p = 0; p < 8; ++p)
      *(u16x8*)&Bs[(srw + p * 8) * MKP + sck] = rb[p];
    // prefetch next K-step (flies under the MFMA section below)
    if (k0 + 64 < KH) { LDA(k0 + 64); LDB(k0 + 64); }
#pragma unroll
    for (int ks = 0; ks < 2; ++ks) {
      s16x8 af[4], bf[4];
#pragma unroll
      for (int mi = 0; mi < 4; ++mi)
        af[mi] = *(const s16x8*)&As[(mi * 16 + l15) * MKP + ks * 32 + l4 * 8];
#pragma unroll
      for (int ni = 0; ni < 4; ++ni)
        bf[ni] = *(const s16x8*)&Bs[(ni * 16 + l15) * MKP + ks * 32 + l4 * 8];
#pragma unroll
      for (int mi = 0; mi < 4; ++mi)
#pragma unroll
        for (int ni = 0; ni < 4; ++ni)
          acc[mi][ni] = __builtin_amdgcn_mfma_f32_16x16x32_bf16(af[mi], bf[ni], acc[mi][ni], 0, 0, 0);
    }
  }

  if constexpr (EPI == 5 || EPI == 6) {
    void* Cb; long cb;
    if (bz < zthr) { Cb = Cq; cb = bz; } else { Cb = C2; cb = bz - zthr; }
    us* Cp = (us*)Cb + (size_t)cb * sC;
    const us* Ep = (const us*)Eq + (size_t)bb * sE;
    epilogue<EPI>(acc, m0, n0, l15, l4, Cp, nullptr, Ep, FX, OG, cp, cidx,
                  ldc, lde, c1, c2);
  } else {
    epilogue<EPI>(acc, m0, n0, l15, l4, Cq, C2, Eq, FX, OG, cp, cidx,
                  ldc, lde, c1, c2);
  }
}

template<int EPI, int TA = 0, int DUAL = 0, int AG = 0, int KS = 1>
static void mg(hipStream_t st, const us* A, const us* A2, const us* B,
               void* C, void* C2, const void* E,
               const float* FX, const float* OG, const float* cp, int cidx,
               int M, int N, int K, int lda, int ldb, int ldc, int lde,
               float c1, float c2, long sA, long sB, long sC, long sE,
               int batch, int zthr = (1 << 30)) {
  dim3 g(N / 64, M / 64, batch * KS), b(64);
  hipLaunchKernelGGL((mg_k<EPI, TA, DUAL, AG, KS>), g, b, 0, st, A, A2, B, C, C2, E,
                     FX, OG, cp, cidx, M, N, K, lda, ldb, ldc, lde, c1, c2,
                     sA, sB, sC, sE, zthr);
}

// ---------------- split-K combines ----------------

// Ab[b][j] = P[b*2][j] + P[b*2+1][j]   (P: [2][2][1024][1024] bf16)
__global__ __launch_bounds__(256) void combA_k(const u16x8* __restrict__ P,
                                               u16x8* __restrict__ Ab) {
  int i = blockIdx.x * 256 + threadIdx.x;          // over 262144
  int b = i >> 17, j = i & 131071;
  u16x8 p0 = P[(size_t)(b * 2) * 131072 + j];
  u16x8 p1 = P[(size_t)(b * 2 + 1) * 131072 + j];
  u16x8 o;
#pragma unroll
  for (int q = 0; q < 8; ++q) o[q] = f2bf(bf2f(p0[q]) + bf2f(p1[q]));
  Ab[i] = o;
}

// Bb[b][j] = nsc*(P0+P1) + nsb*Ab
__global__ __launch_bounds__(256) void combB_k(const u16x8* __restrict__ P,
                                               const u16x8* __restrict__ Ab,
                                               u16x8* __restrict__ Bb,
                                               float nsb, float nsc) {
  int i = blockIdx.x * 256 + threadIdx.x;
  int b = i >> 17, j = i & 131071;
  u16x8 p0 = P[(size_t)(b * 2) * 131072 + j];
  u16x8 p1 = P[(size_t)(b * 2 + 1) * 131072 + j];
  u16x8 ab = Ab[i];
  u16x8 o;
#pragma unroll
  for (int q = 0; q < 8; ++q)
    o[q] = f2bf(nsc * (bf2f(p0[q]) + bf2f(p1[q])) + nsb * bf2f(ab[q]));
  Bb[i] = o;
}

// Xn[b][r][h] = P(b,0)+P(b,1)+nsa*Xc ; XT[b][h][r] = same (if doT).
// Partial p=b*2+s: p==0 -> P0 ; else P1 + (p-1)*SB2. Each partial 1024x2048.
__global__ void combX_k(const us* __restrict__ P0, const us* __restrict__ P1,
                        const us* __restrict__ Xc, us* __restrict__ Xn,
                        us* __restrict__ XT, float nsa, int doT) {
  __shared__ us tile[32][33];
  const long SB2c = 2097152;
  int b = blockIdx.z;
  int h0 = blockIdx.x * 32, r0 = blockIdx.y * 32;
  int tx = threadIdx.x, ty = threadIdx.y;
  const us* pa = (b * 2 == 0) ? P0 : P1 + (size_t)(b * 2 - 1) * SB2c;
  const us* pb = P1 + (size_t)(b * 2) * SB2c;   // p = b*2+1 >= 1 always
  const us* xc = Xc + (size_t)b * SB2c;
  us* xn = Xn + (size_t)b * SB2c;
  us* xt = XT + (size_t)b * SB2c;
#pragma unroll
  for (int j = 0; j < 4; ++j) {
    size_t idx = (size_t)(r0 + ty + 8 * j) * 2048 + h0 + tx;
    float v = bf2f(pa[idx]) + bf2f(pb[idx]) + nsa * bf2f(xc[idx]);
    us uv = f2bf(v);
    xn[idx] = uv;
    tile[ty + 8 * j][tx] = uv;
  }
  __syncthreads();
  if (doT) {
#pragma unroll
    for (int j = 0; j < 4; ++j)
      xt[(size_t)(h0 + ty + 8 * j) * 1024 + r0 + tx] = tile[tx][ty + 8 * j];
  }
}

// ---------------- conversions ----------------

__global__ __launch_bounds__(256) void conv_k(const float* __restrict__ in,
                                              us* __restrict__ out, int n) {
  for (int i = blockIdx.x * 256 + threadIdx.x; i < n; i += gridDim.x * 256)
    out[i] = f2bf(in[i]);
}

__global__ void tconv_k(const float* __restrict__ in, us* __restrict__ out, int R, int C) {
  __shared__ float tile[32][33];
  int c0 = blockIdx.x * 32, r0 = blockIdx.y * 32;
  int tx = threadIdx.x, ty = threadIdx.y;
#pragma unroll
  for (int j = 0; j < 4; ++j)
    tile[ty + 8 * j][tx] = in[(size_t)(r0 + ty + 8 * j) * C + c0 + tx];
  __syncthreads();
#pragma unroll
  for (int j = 0; j < 4; ++j)
    out[(size_t)(c0 + ty + 8 * j) * R + r0 + tx] = f2bf(tile[tx][ty + 8 * j]);
}

// ---------------- elementwise / reductions ----------------

__global__ __launch_bounds__(256) void polynorm2_k(const float* __restrict__ lin,
                                                   us* __restrict__ outp) {
  __shared__ float red[256];
  int n = blockIdx.x, t = threadIdx.x;
  int rowp = cm_map(n);
  float s = 0.f;
  for (int f = t; f < 512; f += 256) { float v = lin[(size_t)n * 512 + f]; s += v * v; }
  float tot = block_reduce_sum(s, red);
  float sc = 1.0f / fmaxf(sqrtf(tot), 1e-12f);
  const float is2 = 0.70710678118654752f;
  for (int f = t; f < 512; f += 256) {
    float v = lin[(size_t)n * 512 + f] * sc;
    outp[(size_t)rowp * 1024 + f] = f2bf(v * is2);
    outp[(size_t)rowp * 1024 + 512 + f] = f2bf(v * v * is2);
  }
}

__global__ __launch_bounds__(256) void gates_k(const float* __restrict__ x,
    const float* __restrict__ wlr, const float* __restrict__ blr,
    const float* __restrict__ wmom, const float* __restrict__ bmom,
    const float* __restrict__ wdec, const float* __restrict__ bdec,
    const float* __restrict__ wgate, const float* __restrict__ bgate,
    float* __restrict__ lrv, float* __restrict__ momv,
    float* __restrict__ decv, float* __restrict__ og) {
  __shared__ float red[256];
  int n = blockIdx.x, t = threadIdx.x;
  float s0 = 0.f, s1 = 0.f, s2 = 0.f, s3 = 0.f;
  for (int d = t; d < 2048; d += 256) {
    float xv = x[(size_t)n * 2048 + d];
    s0 += xv * wlr[d]; s1 += xv * wmom[d]; s2 += xv * wdec[d]; s3 += xv * wgate[d];
  }
  float r0 = block_reduce_sum(s0, red);
  float r1 = block_reduce_sum(s1, red);
  float r2 = block_reduce_sum(s2, red);
  float r3 = block_reduce_sum(s3, red);
  if (t == 0) {
    lrv[n] = sigmoid_f(r0 + blr[0]);
    momv[n] = sigmoid_f(r1 + bmom[0]);
    decv[n] = sigmoid_f(r2 + bdec[0]);
    og[n] = sigmoid_f(r3 + bgate[0]);
  }
}

__global__ void chunk_means_k(const float* __restrict__ lrv, const float* __restrict__ momv,
                              const float* __restrict__ decv, float* __restrict__ cp) {
  int c = blockIdx.x, t = threadIdx.x;  // 64 threads
  int n = ((t >> 5) << 10) + c * 32 + (t & 31);
  float a = lrv[n], b = momv[n], d = decv[n];
  for (int off = 32; off > 0; off >>= 1) {
    a += __shfl_down(a, off);
    b += __shfl_down(b, off);
    d += __shfl_down(d, off);
  }
  if (t == 0) {
    cp[c * 3 + 0] = a * (1.f / 64.f);
    cp[c * 3 + 1] = b * (1.f / 64.f);
    cp[c * 3 + 2] = d * (1.f / 64.f);
  }
}

__global__ __launch_bounds__(256) void sampnorm2_k(const us* __restrict__ kp_b,
                                                   const float* __restrict__ dh,
                                                   const us* __restrict__ hab,
                                                   const us* __restrict__ pr,
                                                   float* __restrict__ w0inv,
                                                   float* __restrict__ w1inv, int c) {
  __shared__ float red[256];
  int i = blockIdx.x, t = threadIdx.x;
  int row = c * 64 + i;
  float sk = 0.f, sr = 0.f, sdh = 0.f, sa = 0.f;
  for (int p = t; p < 1024; p += 256) {
    float v = bf2f(kp_b[(size_t)row * 1024 + p]); sk += v * v;
    v = bf2f(pr[(size_t)(64 + i) * 1024 + p]); sr += v * v;
  }
  for (int h = t; h < 2048; h += 256) {
    float v = dh[(size_t)i * 2048 + h]; sdh += v * v;
    v = bf2f(hab[(size_t)(64 + i) * 2048 + h]); sa += v * v;
  }
  float tk = block_reduce_sum(sk, red);
  float tdh = block_reduce_sum(sdh, red);
  float ta = block_reduce_sum(sa, red);
  float tr = block_reduce_sum(sr, red);
  if (t == 0) {
    float n0 = fmaxf(sqrtf(tk) * sqrtf(tdh), 1e-8f);
    w0inv[i] = 1.0f / (64.0f * fmaxf(n0 * 0.1f, 1.0f));
    float n1 = fmaxf(sqrtf(ta) * sqrtf(tr), 1e-8f);
    w1inv[i] = 1.0f / (64.0f * fmaxf(n1 * 0.1f, 1.0f));
  }
}

template<int INF32>
__global__ void wtrans_k(const void* __restrict__ in, const float* __restrict__ w,
                         us* __restrict__ out, int C, int ldin) {
  __shared__ float tile[32][33];
  int c0 = blockIdx.x * 32, r0 = blockIdx.y * 32;
  int tx = threadIdx.x, ty = threadIdx.y;
#pragma unroll
  for (int j = 0; j < 4; ++j) {
    int r = r0 + ty + 8 * j, cc = c0 + tx;
    float v;
    if constexpr (INF32) v = ((const float*)in)[(size_t)r * ldin + cc];
    else v = bf2f(((const us*)in)[(size_t)r * ldin + cc]);
    tile[ty + 8 * j][tx] = v * w[r];
  }
  __syncthreads();
#pragma unroll
  for (int j = 0; j < 4; ++j)
    out[(size_t)(c0 + ty + 8 * j) * 64 + r0 + tx] = f2bf(tile[tx][ty + 8 * j]);
}

__global__ __launch_bounds__(256) void frob2_k(const float* __restrict__ s0,
                                               const float* __restrict__ s1, int n,
                                               float* __restrict__ parts) {
  __shared__ float red[256];
  const float* s = blockIdx.z ? s1 : s0;
  float acc = 0.f;
  for (int i = blockIdx.x * 256 + threadIdx.x; i < n; i += gridDim.x * 256) {
    float v = s[i]; acc += v * v;
  }
  float r = block_reduce_sum(acc, red);
  if (threadIdx.x == 0) parts[blockIdx.z * 256 + blockIdx.x] = r;
}

__global__ __launch_bounds__(256) void frob_fin2_k(const float* __restrict__ parts,
                                                   float* __restrict__ inv) {
  __shared__ float red[256];
  float r = block_reduce_sum(parts[blockIdx.x * 256 + threadIdx.x], red);
  if (threadIdx.x == 0) inv[blockIdx.x] = 1.0f / (sqrtf(r) + 1e-7f);
}

__global__ void scale_dual_k(const float* __restrict__ in, us* __restrict__ outS,
                             us* __restrict__ outT, const float* __restrict__ inv,
                             int R, int C) {
  __shared__ float tile[32][33];
  float s = *inv;
  int c0 = blockIdx.x * 32, r0 = blockIdx.y * 32;
  int tx = threadIdx.x, ty = threadIdx.y;
#pragma unroll
  for (int j = 0; j < 4; ++j) {
    float v = in[(size_t)(r0 + ty + 8 * j) * C + c0 + tx];
    tile[ty + 8 * j][tx] = v;
    outS[(size_t)(r0 + ty + 8 * j) * C + c0 + tx] = f2bf(v * s);
  }
  __syncthreads();
#pragma unroll
  for (int j = 0; j < 4; ++j)
    outT[(size_t)(c0 + ty + 8 * j) * R + r0 + tx] = f2bf(tile[tx][ty + 8 * j] * s);
}

__global__ void wupd0_k(float* __restrict__ W0, const us* __restrict__ X,
                        us* __restrict__ W0bT, const float* __restrict__ cp, int c) {
  __shared__ float tl[32][33];
  float lr = cp[c * 3 + 0], om = 1.0f - cp[c * 3 + 2];
  int c0 = blockIdx.x * 32, r0 = blockIdx.y * 32;
  int tx = threadIdx.x, ty = threadIdx.y;
#pragma unroll
  for (int j = 0; j < 4; ++j) {
    int r = r0 + ty + 8 * j, h = c0 + tx;
    size_t idx = (size_t)r * 2048 + h;
    float v = om * W0[idx] + lr * bf2f(X[idx]);
    W0[idx] = v;
    tl[ty + 8 * j][tx] = v;
  }
  __syncthreads();
#pragma unroll
  for (int j = 0; j < 4; ++j)
    W0bT[(size_t)(c0 + ty + 8 * j) * 1024 + r0 + tx] = f2bf(tl[tx][ty + 8 * j]);
}

__global__ void wupd1_k(float* __restrict__ W1, const us* __restrict__ X2,
                        us* __restrict__ W1b, us* __restrict__ W1bT,
                        const float* __restrict__ cp, int c) {
  __shared__ float tX[32][33];
  __shared__ float t2[32][33];
  float lr = cp[c * 3 + 0], om = 1.0f - cp[c * 3 + 2];
  int h0 = blockIdx.x * 32, p0 = blockIdx.y * 32;
  int tx = threadIdx.x, ty = threadIdx.y;
#pragma unroll
  for (int j = 0; j < 4; ++j)
    tX[ty + 8 * j][tx] = bf2f(X2[(size_t)(p0 + ty + 8 * j) * 2048 + h0 + tx]);
  __syncthreads();
#pragma unroll
  for (int j = 0; j < 4; ++j) {
    int h = h0 + ty + 8 * j, p = p0 + tx;
    size_t idx = (size_t)h * 1024 + p;
    float v = om * W1[idx] + lr * tX[tx][ty + 8 * j];
    W1[idx] = v;
    W1b[idx] = f2bf(v);
    t2[tx][ty + 8 * j] = v;
  }
  __syncthreads();
#pragma unroll
  for (int j = 0; j < 4; ++j)
    W1bT[(size_t)(p0 + ty + 8 * j) * 2048 + h0 + tx] = f2bf(t2[ty + 8 * j][tx]);
}

// ---------------- host ----------------

extern "C" void kernel_launch(void* const* d_in, const int* in_sizes, int n_in,
                              void* d_out, int out_size, void* d_ws, size_t ws_size,
                              hipStream_t stream) {
  const float* x = (const float*)d_in[0];
  const float* Wk = (const float*)d_in[1];
  const float* Wv = (const float*)d_in[2];
  const float* Wq = (const float*)d_in[3];
  const float* Wout = (const float*)d_in[4];
  const float* w_lr = (const float*)d_in[5];
  const float* b_lr = (const float*)d_in[6];
  const float* w_mom = (const float*)d_in[7];
  const float* b_mom = (const float*)d_in[8];
  const float* w_dec = (const float*)d_in[9];
  const float* b_dec = (const float*)d_in[10];
  const float* w_gate = (const float*)d_in[11];
  const float* b_gate = (const float*)d_in[12];
  const float* Wmem0 = (const float*)d_in[13];
  const float* Wmem1 = (const float*)d_in[14];
  const float* Wmemout = (const float*)d_in[15];
  const float* Wvexp = (const float*)d_in[16];
  float* out = (float*)d_out;
  (void)n_in; (void)in_sizes; (void)out_size;

  const long F = 1048576;
  const long BIG = 2097152;
  const long SB2 = 2097152, SB1 = 1048576;
  float* ws = (float*)d_ws;
  if (ws_size < (size_t)25043464 * sizeof(float)) return;

  us* kp_b   = (us*)ws;               // [0,1F)
  us* qp_b   = (us*)(ws + F);         // [1,2)
  float* vexp = ws + 2 * F;           // [2,4)
  float* W0  = ws + 4 * F;            // [4,6)
  float* W1  = ws + 6 * F;            // [6,8)
  float* S0  = ws + 8 * F;            // [8,10)
  float* S1  = ws + 10 * F;           // [10,12)
  us* XA     = (us*)(ws + 12 * F);    // [12,14)
  us* XB     = (us*)(ws + 14 * F);    // [14,16)
  us* XT     = (us*)(ws + 16 * F);    // [16,18)
  us* Ab     = (us*)(ws + 18 * F);    // [18,19)
  float* SCR = ws + 19 * F;           // [19,20)
  us* W0bT   = (us*)(ws + 20 * F);    // [20,21)  (dead during NS -> BX partials)
  us* W1bT   = (us*)(ws + 21 * F);    // [21,22)  (dead during NS -> BX partials)
  us* W1b    = (us*)(ws + 22 * F);    // [22,23)  (dead during NS -> BX partials)
  us* WmoT   = (us*)(ws + 23 * F);    // [23,23.25)
  us* retrv  = (us*)(ws + 23 * F + 262144);
  float* smal = ws + 23 * F + 262144 + 524288;
  float* og   = smal;
  float* lrv  = og + 2048;
  float* momv = lrv + 2048;
  float* decv = momv + 2048;
  float* cpb  = decv + 2048;
  float* w0inv = cpb + 128;
  float* w1inv = w0inv + 64;
  float* parts = w1inv + 64;
  float* inv01 = parts + 512;

  us* xb   = XA;
  us* Wkb  = XB;
  us* Wqb  = XB + 1048576;
  us* Wvb  = XB + 2097152;
  us* vlin = XT;
  us* WvexpT = XT + 1048576;
  us* Woutb = Ab;
  float* lin = SCR;
  us* Bb = (us*)SCR;
  us* hab   = (us*)SCR;
  float* gp = SCR + 131072;
  us* pr    = (us*)(SCR + 262144);
  float* dh = SCR + 327680;
  us* dhT   = (us*)(SCR + 458752);
  us* rbwT  = (us*)(SCR + 524288);

  const float NSa = 3.4445f, NSb = -4.7750f, NSc = 2.0315f;

  hipMemcpyAsync(W0, Wmem0, (size_t)BIG * 4, hipMemcpyDeviceToDevice, stream);
  hipMemcpyAsync(W1, Wmem1, (size_t)BIG * 4, hipMemcpyDeviceToDevice, stream);
  hipMemsetAsync(S0, 0, (size_t)BIG * 4, stream);
  hipMemsetAsync(S1, 0, (size_t)BIG * 4, stream);
  hipLaunchKernelGGL(tconv_k, dim3(64, 32), dim3(32, 8), 0, stream, Wmem0, W0bT, 1024, 2048);
  hipLaunchKernelGGL(conv_k, dim3(1024), dim3(256), 0, stream, Wmem1, W1b, (int)BIG);
  hipLaunchKernelGGL(tconv_k, dim3(32, 64), dim3(32, 8), 0, stream, Wmem1, W1bT, 2048, 1024);
  hipLaunchKernelGGL(tconv_k, dim3(16, 32), dim3(32, 8), 0, stream, Wmemout, WmoT, 1024, 512);
  hipLaunchKernelGGL(tconv_k, dim3(32, 16), dim3(32, 8), 0, stream, Wvexp, WvexpT, 512, 1024);
  hipLaunchKernelGGL(conv_k, dim3(2048), dim3(256), 0, stream, x, xb, 2048 * 2048);
  hipLaunchKernelGGL(conv_k, dim3(512), dim3(256), 0, stream, Wk, Wkb, 512 * 2048);
  hipLaunchKernelGGL(conv_k, dim3(512), dim3(256), 0, stream, Wq, Wqb, 512 * 2048);
  hipLaunchKernelGGL(conv_k, dim3(512), dim3(256), 0, stream, Wv, Wvb, 512 * 2048);

  mg<7>(stream, xb, nullptr, Wkb, lin, nullptr, nullptr, nullptr, nullptr, nullptr, 0,
        2048, 512, 2048, 2048, 2048, 512, 0, 0.f, 0.f, 0, 0, 0, 0, 1);
  hipLaunchKernelGGL(polynorm2_k, dim3(2048), dim3(256), 0, stream, lin, kp_b);
  mg<7>(stream, xb, nullptr, Wqb, lin, nullptr, nullptr, nullptr, nullptr, nullptr, 0,
        2048, 512, 2048, 2048, 2048, 512, 0, 0.f, 0.f, 0, 0, 0, 0, 1);
  hipLaunchKernelGGL(polynorm2_k, dim3(2048), dim3(256), 0, stream, lin, qp_b);
  mg<5>(stream, xb, nullptr, Wvb, vlin, nullptr, nullptr, nullptr, nullptr, nullptr, 0,
        2048, 512, 2048, 2048, 2048, 512, 0, 0.f, 0.f, 0, 0, 0, 0, 1);
  mg<17>(stream, vlin, nullptr, WvexpT, vexp, nullptr, nullptr, nullptr, nullptr, nullptr, 0,
         2048, 1024, 512, 512, 512, 1024, 0, 0.f, 0.f, 0, 0, 0, 0, 1);

  hipLaunchKernelGGL(gates_k, dim3(2048), dim3(256), 0, stream, x,
                     w_lr, b_lr, w_mom, b_mom, w_dec, b_dec, w_gate, b_gate,
                     lrv, momv, decv, og);
  hipLaunchKernelGGL(chunk_means_k, dim3(32), dim3(64), 0, stream, lrv, momv, decv, cpb);

  for (int c = 0; c < 32; ++c) {
    const us* kp_c = kp_b + (size_t)c * 64 * 1024;
    const us* qp_c = qp_b + (size_t)c * 64 * 1024;
    const float* vexp_c = vexp + (size_t)c * 64 * 1024;
    mg<8, 0, 1>(stream, qp_c, kp_c, W0bT, hab, gp, nullptr, nullptr, nullptr, nullptr, 0,
                128, 2048, 1024, 1024, 1024, 2048, 0, 0.f, 0.f, 0, 0, 0, 0, 1);
    mg<9>(stream, hab, nullptr, W1bT, pr, nullptr, vexp_c, nullptr, nullptr, nullptr, 0,
          128, 1024, 2048, 2048, 2048, 1024, 1024, 0.f, 0.f, 0, 0, 0, 0, 1);
    mg<5>(stream, pr, nullptr, WmoT, retrv + (size_t)c * 64 * 512, nullptr, nullptr,
          nullptr, nullptr, nullptr, 0,
          64, 512, 1024, 1024, 1024, 512, 0, 0.f, 0.f, 0, 0, 0, 0, 1);
    mg<13>(stream, pr + 64 * 1024, nullptr, W1b, dh, nullptr, gp, nullptr, nullptr, nullptr, 0,
           64, 2048, 1024, 1024, 1024, 2048, 2048, 0.f, 0.f, 0, 0, 0, 0, 1);
    hipLaunchKernelGGL(sampnorm2_k, dim3(64), dim3(256), 0, stream,
                       kp_b, dh, hab, pr, w0inv, w1inv, c);
    hipLaunchKernelGGL((wtrans_k<1>), dim3(64, 2), dim3(32, 8), 0, stream, dh, w0inv, dhT, 2048, 2048);
    hipLaunchKernelGGL((wtrans_k<0>), dim3(32, 2), dim3(32, 8), 0, stream, pr + 64 * 1024, w1inv,
                       rbwT, 1024, 1024);
    mg<14, 1>(stream, kp_c, nullptr, dhT, S0, nullptr, nullptr, nullptr, nullptr, cpb, c,
              1024, 2048, 64, 1024, 64, 2048, 0, 0.f, 0.f, 0, 0, 0, 0, 1);
    mg<14, 1>(stream, hab + 64 * 2048, nullptr, rbwT, S1, nullptr, nullptr, nullptr, nullptr, cpb, c,
              2048, 1024, 64, 2048, 64, 1024, 0, 0.f, 0.f, 0, 0, 0, 0, 1);

    // ---- batched NS5: batch0 = S0 (1024x2048), batch1 = S1^T ----
    hipLaunchKernelGGL(frob2_k, dim3(256, 1, 2), dim3(256), 0, stream, S0, S1, (int)BIG, parts);
    hipLaunchKernelGGL(frob_fin2_k, dim3(2), dim3(256), 0, stream, parts, inv01);
    hipLaunchKernelGGL(scale_dual_k, dim3(64, 32), dim3(32, 8), 0, stream,
                       S0, XA, XT, inv01, 1024, 2048);
    hipLaunchKernelGGL(scale_dual_k, dim3(32, 64), dim3(32, 8), 0, stream,
                       S1, XT + SB2, XA + SB2, inv01 + 1, 2048, 1024);

    us* Xc = XA;
    us* Xn = XB;
    for (int it = 0; it < 5; ++it) {
      us* P = Xn;  // dead until combX writes it: [2][2][1024][1024] partials
      // XX^T split-K=2 -> P
      mg<5, 0, 0, 0, 2>(stream, Xc, nullptr, Xc, P, nullptr, nullptr,
                        nullptr, nullptr, nullptr, 0,
                        1024, 1024, 2048, 2048, 2048, 1024, 0, 0.f, 0.f,
                        SB2, SB2, SB1, 0, 2);
      hipLaunchKernelGGL(combA_k, dim3(1024), dim3(256), 0, stream,
                         (const u16x8*)P, (u16x8*)Ab);
      // AA split-K=2 -> P
      mg<5, 0, 0, 0, 2>(stream, Ab, nullptr, Ab, P, nullptr, nullptr,
                        nullptr, nullptr, nullptr, 0,
                        1024, 1024, 1024, 1024, 1024, 1024, 0, 0.f, 0.f,
                        SB1, SB1, SB1, 0, 2);
      hipLaunchKernelGGL(combB_k, dim3(1024), dim3(256), 0, stream,
                         (const u16x8*)P, (const u16x8*)Ab, (u16x8*)Bb, NSb, NSc);
      // BX split-K=2 -> partials: bz0 -> Ab region; bz1..3 -> W0bT region
      mg<5, 0, 0, 0, 2>(stream, Bb, nullptr, XT, Ab, W0bT, nullptr,
                        nullptr, nullptr, nullptr, 0,
                        1024, 2048, 1024, 1024, 1024, 2048, 0, 0.f, 0.f,
                        SB1, SB2, SB2, 0, 2, 1);
      // Xn = sum partials + NSa*Xc ; XT = Xn^T (skip on last iter)
      hipLaunchKernelGGL(combX_k, dim3(64, 32, 2), dim3(32, 8), 0, stream,
                         Ab, W0bT, Xc, Xn, XT, NSa, it < 4 ? 1 : 0);
      us* tmp = Xc; Xc = Xn; Xn = tmp;
    }
    hipLaunchKernelGGL(wupd0_k, dim3(64, 32), dim3(32, 8), 0, stream, W0, Xc, W0bT, cpb, c);
    hipLaunchKernelGGL(wupd1_k, dim3(64, 32), dim3(32, 8), 0, stream, W1, Xc + SB2, W1b, W1bT, cpb, c);
  }

  hipLaunchKernelGGL(conv_k, dim3(1024), dim3(256), 0, stream, Wout, Woutb, 2048 * 512);
  mg<15, 0, 0, 1>(stream, retrv, nullptr, Woutb, out, nullptr, nullptr, x, og, nullptr, 0,
                  2048, 2048, 512, 512, 512, 2048, 0, 0.f, 0.f, 0, 0, 0, 0, 1);
}

// Round 12
// 17164.119 us; speedup vs baseline: 1.2135x; 1.0037x over previous
//
#include <hip/hip_runtime.h>

// ---------------------------------------------------------------------------
// DeepMemoryLevel (ATLAS-style). B=2 S=1024 D=2048 M=512 P=1024 H=2048
// CHUNK=32 NC=32, tokens N=2048.
// Round 12: NS5 GEMMs use LDS-FREE packed-fragment operands (mgf_k):
// operands stored in MFMA fragment order so each frag load is a fully
// coalesced 1KB wave instruction. DS-unit bottleneck of the 1-wave LDS GEMM
// (32 DS instr/K-step) eliminated. Packing folded into producers:
// scalepk (S -> Xc + XP/XTP), pack-epilogues (XX^T -> AP, AA -> BP fused
// NS combine), packX after BX. No split-K. Chunk path = R7 LDS kernel.
// ---------------------------------------------------------------------------

typedef unsigned short us;
typedef __attribute__((ext_vector_type(8))) short s16x8;
typedef __attribute__((ext_vector_type(8))) unsigned short u16x8;
typedef __attribute__((ext_vector_type(4))) float f32x4;

#define MKP 72

__device__ __forceinline__ float gelu_f(float x) {
  return 0.5f * x * (1.0f + erff(x * 0.70710678118654752f));
}
__device__ __forceinline__ float gelu_grad_f(float x) {
  float cdf = 0.5f * (1.0f + erff(x * 0.70710678118654752f));
  float pdf = 0.3989422804014327f * expf(-0.5f * x * x);
  return cdf + x * pdf;
}
__device__ __forceinline__ float sigmoid_f(float x) { return 1.0f / (1.0f + expf(-x)); }

__device__ __forceinline__ us f2bf(float f) {
  union { float f; unsigned u; } v; v.f = f;
  unsigned r = (v.u + 0x7FFFu + ((v.u >> 16) & 1u)) >> 16;
  return (us)r;
}
__device__ __forceinline__ float bf2f(us h) {
  union { unsigned u; float f; } v; v.u = ((unsigned)h) << 16;
  return v.f;
}
// token-major index n -> chunk-major row
__device__ __forceinline__ int cm_map(int n) {
  return ((n & 1023) >> 5) * 64 + (n >> 10) * 32 + (n & 31);
}
// packed-fragment offset: matrix R x K (row-major source), element (r,k).
__device__ __forceinline__ size_t pf_off(int r, int k, int KB) {
  return ((size_t)(r >> 4) * KB + (k >> 5)) * 512 + ((k >> 3) & 3) * 128 + (r & 15) * 8 + (k & 7);
}

__device__ __forceinline__ float block_reduce_sum(float v, float* red) {
  int t = threadIdx.x;
  red[t] = v; __syncthreads();
  for (int s = blockDim.x >> 1; s > 0; s >>= 1) {
    if (t < s) red[t] += red[t + s];
    __syncthreads();
  }
  float r = red[0];
  __syncthreads();
  return r;
}

// ---------------- packed-fragment 1-wave 64x64 MFMA GEMM (no LDS K-loop) ----
// A_pf: packed (M x K); B_pf: packed (N x K)  [B math = Bsrc^T].
// EPI 20: C packed = acc (bf16).
// EPI 21: C packed = c1*acc + c2*E_packed.
// EPI 6 : C row-major us = c1*acc + c2*bf(E row-major us), ldc stride.
template<int EPI>
__global__ __launch_bounds__(64)
void mgf_k(const us* __restrict__ Apf, const us* __restrict__ Bpf,
           us* __restrict__ Cq, const us* __restrict__ Eq,
           int M, int N, int K, int ldc,
           float c1, float c2, long sA, long sB, long sC, long sE) {
  __shared__ __align__(16) us ct[4096];
  const int bz = blockIdx.z;
  const us* A = Apf + (size_t)bz * sA;
  const us* B = Bpf + (size_t)bz * sB;
  us* C = Cq + (size_t)bz * sC;
  const us* E = Eq + (size_t)bz * sE;
  const int lane = threadIdx.x;
  const int m0 = blockIdx.y * 64, n0 = blockIdx.x * 64;
  const int KB = K >> 5;
  const int l15 = lane & 15, l4 = lane >> 4;

  const us* am[4];
  const us* bm[4];
#pragma unroll
  for (int q = 0; q < 4; ++q) {
    am[q] = A + ((size_t)((m0 >> 4) + q) * KB) * 512 + lane * 8;
    bm[q] = B + ((size_t)((n0 >> 4) + q) * KB) * 512 + lane * 8;
  }

  f32x4 acc[4][4];
#pragma unroll
  for (int i = 0; i < 4; ++i)
#pragma unroll
    for (int j = 0; j < 4; ++j) acc[i][j] = (f32x4){0.f, 0.f, 0.f, 0.f};

  u16x8 a0[4], b0[4], a1[4], b1[4];
#pragma unroll
  for (int q = 0; q < 4; ++q) {
    a0[q] = *(const u16x8*)(am[q]);
    b0[q] = *(const u16x8*)(bm[q]);
    a1[q] = *(const u16x8*)(am[q] + 512);
    b1[q] = *(const u16x8*)(bm[q] + 512);
  }

  for (int kb = 0; kb < KB; kb += 2) {
#pragma unroll
    for (int mi = 0; mi < 4; ++mi)
#pragma unroll
      for (int ni = 0; ni < 4; ++ni)
        acc[mi][ni] = __builtin_amdgcn_mfma_f32_16x16x32_bf16(
            (s16x8)a0[mi], (s16x8)b0[ni], acc[mi][ni], 0, 0, 0);
    if (kb + 2 < KB) {
#pragma unroll
      for (int q = 0; q < 4; ++q) {
        a0[q] = *(const u16x8*)(am[q] + (size_t)(kb + 2) * 512);
        b0[q] = *(const u16x8*)(bm[q] + (size_t)(kb + 2) * 512);
      }
    }
#pragma unroll
    for (int mi = 0; mi < 4; ++mi)
#pragma unroll
      for (int ni = 0; ni < 4; ++ni)
        acc[mi][ni] = __builtin_amdgcn_mfma_f32_16x16x32_bf16(
            (s16x8)a1[mi], (s16x8)b1[ni], acc[mi][ni], 0, 0, 0);
    if (kb + 3 < KB) {
#pragma unroll
      for (int q = 0; q < 4; ++q) {
        a1[q] = *(const u16x8*)(am[q] + (size_t)(kb + 3) * 512);
        b1[q] = *(const u16x8*)(bm[q] + (size_t)(kb + 3) * 512);
      }
    }
  }

  if constexpr (EPI == 6) {
#pragma unroll
    for (int mi = 0; mi < 4; ++mi) {
#pragma unroll
      for (int i = 0; i < 4; ++i) {
        int grow = m0 + mi * 16 + l4 * 4 + i;
#pragma unroll
        for (int ni = 0; ni < 4; ++ni) {
          int col = n0 + ni * 16 + l15;
          float v = acc[mi][ni][i];
          C[(size_t)grow * ldc + col] =
              f2bf(c1 * v + c2 * bf2f(E[(size_t)grow * ldc + col]));
        }
      }
    }
  } else {
    // stage tile into LDS row-major (1 wave: in-order DS, no barrier)
#pragma unroll
    for (int mi = 0; mi < 4; ++mi)
#pragma unroll
      for (int i = 0; i < 4; ++i)
#pragma unroll
        for (int ni = 0; ni < 4; ++ni)
          ct[(mi * 16 + l4 * 4 + i) * 64 + ni * 16 + l15] = f2bf(acc[mi][ni][i]);
    const int KC = N >> 5;  // packed col-blocks of output
#pragma unroll
    for (int q = 0; q < 8; ++q) {
      int cid = lane * 8 + q;
      int r = cid >> 3, kc = cid & 7;
      u16x8 v = *(const u16x8*)&ct[r * 64 + kc * 8];
      size_t off = pf_off(m0 + r, n0 + kc * 8, KC);
      if constexpr (EPI == 21) {
        u16x8 e = *(const u16x8*)(E + off);
        u16x8 o;
#pragma unroll
        for (int w = 0; w < 8; ++w) o[w] = f2bf(c1 * bf2f(v[w]) + c2 * bf2f(e[w]));
        *(u16x8*)(C + off) = o;
      } else {
        *(u16x8*)(C + off) = v;
      }
    }
  }
}

template<int EPI>
static void mgf(hipStream_t st, const us* A, const us* B, us* C, const us* E,
                int M, int N, int K, int ldc, float c1, float c2,
                long sA, long sB, long sC, long sE) {
  dim3 g(N / 64, M / 64, 2), b(64);
  hipLaunchKernelGGL((mgf_k<EPI>), g, b, 0, st, A, B, C, E, M, N, K, ldc,
                     c1, c2, sA, sB, sC, sE);
}

// ---------------- epilogue for LDS GEMM (chunk path) ----------------
// EPI: 5 C us=acc | 7 C f32=acc | 8 gelu(+gelu' rows>=64) | 9 pred/resid |
//      13 C f32=acc*E | 14 C f32=mom*C-lr*acc | 15 out=FX+acc*OG | 17 scatter
template<int EPI>
__device__ __forceinline__ void epilogue(f32x4 (&acc)[4][4], int m0, int n0,
    int l15, int l4, void* Cq, void* C2, const void* Eq,
    const float* FX, const float* OG, const float* cp, int cidx,
    int ldc, int lde, float c1, float c2) {
#pragma unroll
  for (int mi = 0; mi < 4; ++mi) {
#pragma unroll
    for (int i = 0; i < 4; ++i) {
      int grow = m0 + mi * 16 + l4 * 4 + i;
#pragma unroll
      for (int ni = 0; ni < 4; ++ni) {
        int col = n0 + ni * 16 + l15;
        float v = acc[mi][ni][i];
        if constexpr (EPI == 5) {
          ((us*)Cq)[(size_t)grow * ldc + col] = f2bf(v);
        } else if constexpr (EPI == 7) {
          ((float*)Cq)[(size_t)grow * ldc + col] = v;
        } else if constexpr (EPI == 8) {
          ((us*)Cq)[(size_t)grow * ldc + col] = f2bf(gelu_f(v));
          if (m0 >= 64)
            ((float*)C2)[(size_t)(grow - 64) * ldc + col] = gelu_grad_f(v);
        } else if constexpr (EPI == 9) {
          if (m0 < 64)
            ((us*)Cq)[(size_t)grow * ldc + col] = f2bf(v);
          else
            ((us*)Cq)[(size_t)grow * ldc + col] =
                f2bf(2.0f * (v - ((const float*)Eq)[(size_t)(grow - 64) * lde + col]));
        } else if constexpr (EPI == 13) {
          ((float*)Cq)[(size_t)grow * ldc + col] =
              v * ((const float*)Eq)[(size_t)grow * lde + col];
        } else if constexpr (EPI == 14) {
          float* C = (float*)Cq;
          float old = C[(size_t)grow * ldc + col];
          C[(size_t)grow * ldc + col] = cp[cidx * 3 + 1] * old - cp[cidx * 3 + 0] * v;
        } else if constexpr (EPI == 15) {
          ((float*)Cq)[(size_t)grow * ldc + col] =
              FX[(size_t)grow * ldc + col] + v * OG[grow];
        } else if constexpr (EPI == 17) {
          int crow = cm_map(grow);
          ((float*)Cq)[(size_t)crow * ldc + col] = v;
        }
      }
    }
  }
}

// ---------------- 1-wave 64x64 bf16 MFMA GEMM (barrier-free, chunk path) ----
template<int EPI, int TA, int DUAL, int AG>
__global__ __launch_bounds__(64)
void mg_k(const us* __restrict__ Aq, const us* __restrict__ A2,
          const us* __restrict__ Bq, void* __restrict__ Cq,
          void* __restrict__ C2, const void* __restrict__ Eq,
          const float* __restrict__ FX, const float* __restrict__ OG,
          const float* __restrict__ cp, int cidx,
          int M, int N, int K, int lda, int ldb, int ldc, int lde,
          float c1, float c2) {
  __shared__ __align__(16) us As[64 * MKP];
  __shared__ __align__(16) us Bs[64 * MKP];
  const us* A = Aq;
  const us* B = Bq;
  const int t = threadIdx.x;
  const int m0 = blockIdx.y * 64, n0 = blockIdx.x * 64;
  if constexpr (DUAL) { if (m0 >= 64) A = A2; }
  const int mA0 = DUAL ? (m0 & 63) : m0;
  const int l15 = t & 15, l4 = t >> 4;

  f32x4 acc[4][4];
#pragma unroll
  for (int i = 0; i < 4; ++i)
#pragma unroll
    for (int j = 0; j < 4; ++j) acc[i][j] = (f32x4){0.f, 0.f, 0.f, 0.f};

  const int srw = t >> 3;
  const int sck = (t & 7) * 8;

  u16x8 ra[8], rb[8];
  auto LDA = [&](int k0) {
#pragma unroll
    for (int p = 0; p < 8; ++p) {
      if constexpr (TA == 0) {
        int row = srw + p * 8;
        int srow;
        if constexpr (AG) srow = cm_map(m0 + row); else srow = mA0 + row;
        ra[p] = *(const u16x8*)(A + (size_t)srow * lda + k0 + sck);
      } else {
        ra[p] = *(const u16x8*)(A + (size_t)(k0 + srw + p * 8) * lda + mA0 + sck);
      }
    }
  };
  auto LDB = [&](int k0) {
#pragma unroll
    for (int p = 0; p < 8; ++p)
      rb[p] = *(const u16x8*)(B + (size_t)(n0 + srw + p * 8) * ldb + k0 + sck);
  };

  LDA(0); LDB(0);
  for (int k0 = 0; k0 < K; k0 += 64) {
    if constexpr (TA == 0) {
#pragma unroll
      for (int p = 0; p < 8; ++p)
        *(u16x8*)&As[(srw + p * 8) * MKP + sck] = ra[p];
    } else {
#pragma unroll
      for (int p = 0; p < 8; ++p) {
        int kk = srw + p * 8;
#pragma unroll
        for (int j = 0; j < 8; ++j) As[(sck + j) * MKP + kk] = ra[p][j];
      }
    }
#pragma unroll
    for (int p = 0; p < 8; ++p)
      *(u16x8*)&Bs[(srw + p * 8) * MKP + sck] = rb[p];
    if (k0 + 64 < K) { LDA(k0 + 64); LDB(k0 + 64); }
#pragma unroll
    for (int ks = 0; ks < 2; ++ks) {
      s16x8 af[4], bf[4];
#pragma unroll
      for (int mi = 0; mi < 4; ++mi)
        af[mi] = *(const s16x8*)&As[(mi * 16 + l15) * MKP + ks * 32 + l4 * 8];
#pragma unroll
      for (int ni = 0; ni < 4; ++ni)
        bf[ni] = *(const s16x8*)&Bs[(ni * 16 + l15) * MKP + ks * 32 + l4 * 8];
#pragma unroll
      for (int mi = 0; mi < 4; ++mi)
#pragma unroll
        for (int ni = 0; ni < 4; ++ni)
          acc[mi][ni] = __builtin_amdgcn_mfma_f32_16x16x32_bf16(af[mi], bf[ni], acc[mi][ni], 0, 0, 0);
    }
  }

  epilogue<EPI>(acc, m0, n0, l15, l4, Cq, C2, Eq, FX, OG, cp, cidx,
                ldc, lde, c1, c2);
}

template<int EPI, int TA = 0, int DUAL = 0, int AG = 0>
static void mg(hipStream_t st, const us* A, const us* A2, const us* B,
               void* C, void* C2, const void* E,
               const float* FX, const float* OG, const float* cp, int cidx,
               int M, int N, int K, int lda, int ldb, int ldc, int lde,
               float c1 = 0.f, float c2 = 0.f) {
  dim3 g(N / 64, M / 64, 1), b(64);
  hipLaunchKernelGGL((mg_k<EPI, TA, DUAL, AG>), g, b, 0, st, A, A2, B, C, C2, E,
                     FX, OG, cp, cidx, M, N, K, lda, ldb, ldc, lde, c1, c2);
}

// ---------------- scale + pack: S f32 [R][C] -> Xrm + XP + XTP ----------------
// TR=0: Xrm = S*s row-major [R][C]; XP = pack(S*s); XTP = pack((S*s)^T).
// TR=1: Xrm = (S*s)^T row-major [C][R]; XP = pack((S*s)^T); XTP = pack(S*s).
template<int TR>
__global__ void scalepk_k(const float* __restrict__ S, const float* __restrict__ inv,
                          us* __restrict__ Xrm, us* __restrict__ XP,
                          us* __restrict__ XTP, int R, int C) {
  __shared__ float tile[32][33];
  float s = *inv;
  int c0 = blockIdx.x * 32, r0 = blockIdx.y * 32;
  int tx = threadIdx.x, ty = threadIdx.y;  // 32 x 8
#pragma unroll
  for (int j = 0; j < 4; ++j)
    tile[ty + 8 * j][tx] = S[(size_t)(r0 + ty + 8 * j) * C + c0 + tx] * s;
  __syncthreads();
  int t = ty * 32 + tx;
  if (t < 128) {
    int rh = t >> 2, cc = t & 3;
    u16x8 v;
#pragma unroll
    for (int e = 0; e < 8; ++e) v[e] = f2bf(tile[rh][cc * 8 + e]);
    int grow = r0 + rh, gcol = c0 + cc * 8;
    size_t offD = pf_off(grow, gcol, C >> 5);
    if constexpr (TR == 0) {
      *(u16x8*)(XP + offD) = v;
      *(u16x8*)(Xrm + (size_t)grow * C + gcol) = v;
    } else {
      *(u16x8*)(XTP + offD) = v;
    }
  } else {
    int ch = (t - 128) >> 2, rc = (t - 128) & 3;
    u16x8 v;
#pragma unroll
    for (int e = 0; e < 8; ++e) v[e] = f2bf(tile[rc * 8 + e][ch]);
    int trow = c0 + ch, tcol = r0 + rc * 8;
    size_t offT = pf_off(trow, tcol, R >> 5);
    if constexpr (TR == 0) {
      *(u16x8*)(XTP + offT) = v;
    } else {
      *(u16x8*)(XP + offT) = v;
      *(u16x8*)(Xrm + (size_t)trow * R + tcol) = v;
    }
  }
}

// ---------------- pack Xn row-major [1024][2048] -> XP + XTP (batched) ------
__global__ void packX_k(const us* __restrict__ Xn, us* __restrict__ XP,
                        us* __restrict__ XTP) {
  __shared__ us tile[32][33];
  const long SB2c = 2097152;
  size_t bo = (size_t)blockIdx.z * SB2c;
  int c0 = blockIdx.x * 32, r0 = blockIdx.y * 32;
  int tx = threadIdx.x, ty = threadIdx.y;  // 32 x 8
#pragma unroll
  for (int j = 0; j < 4; ++j)
    tile[ty + 8 * j][tx] = Xn[bo + (size_t)(r0 + ty + 8 * j) * 2048 + c0 + tx];
  __syncthreads();
  int t = ty * 32 + tx;
  if (t < 128) {
    int rh = t >> 2, cc = t & 3;
    u16x8 v;
#pragma unroll
    for (int e = 0; e < 8; ++e) v[e] = tile[rh][cc * 8 + e];
    size_t offD = pf_off(r0 + rh, c0 + cc * 8, 64);      // 2048/32
    *(u16x8*)(XP + bo + offD) = v;
  } else {
    int ch = (t - 128) >> 2, rc = (t - 128) & 3;
    u16x8 v;
#pragma unroll
    for (int e = 0; e < 8; ++e) v[e] = tile[rc * 8 + e][ch];
    size_t offT = pf_off(c0 + ch, r0 + rc * 8, 32);      // 1024/32
    *(u16x8*)(XTP + bo + offT) = v;
  }
}

// ---------------- conversions ----------------

__global__ __launch_bounds__(256) void conv_k(const float* __restrict__ in,
                                              us* __restrict__ out, int n) {
  for (int i = blockIdx.x * 256 + threadIdx.x; i < n; i += gridDim.x * 256)
    out[i] = f2bf(in[i]);
}

__global__ void tconv_k(const float* __restrict__ in, us* __restrict__ out, int R, int C) {
  __shared__ float tile[32][33];
  int c0 = blockIdx.x * 32, r0 = blockIdx.y * 32;
  int tx = threadIdx.x, ty = threadIdx.y;
#pragma unroll
  for (int j = 0; j < 4; ++j)
    tile[ty + 8 * j][tx] = in[(size_t)(r0 + ty + 8 * j) * C + c0 + tx];
  __syncthreads();
#pragma unroll
  for (int j = 0; j < 4; ++j)
    out[(size_t)(c0 + ty + 8 * j) * R + r0 + tx] = f2bf(tile[tx][ty + 8 * j]);
}

// ---------------- elementwise / reductions ----------------

__global__ __launch_bounds__(256) void polynorm2_k(const float* __restrict__ lin,
                                                   us* __restrict__ outp) {
  __shared__ float red[256];
  int n = blockIdx.x, t = threadIdx.x;
  int rowp = cm_map(n);
  float s = 0.f;
  for (int f = t; f < 512; f += 256) { float v = lin[(size_t)n * 512 + f]; s += v * v; }
  float tot = block_reduce_sum(s, red);
  float sc = 1.0f / fmaxf(sqrtf(tot), 1e-12f);
  const float is2 = 0.70710678118654752f;
  for (int f = t; f < 512; f += 256) {
    float v = lin[(size_t)n * 512 + f] * sc;
    outp[(size_t)rowp * 1024 + f] = f2bf(v * is2);
    outp[(size_t)rowp * 1024 + 512 + f] = f2bf(v * v * is2);
  }
}

__global__ __launch_bounds__(256) void gates_k(const float* __restrict__ x,
    const float* __restrict__ wlr, const float* __restrict__ blr,
    const float* __restrict__ wmom, const float* __restrict__ bmom,
    const float* __restrict__ wdec, const float* __restrict__ bdec,
    const float* __restrict__ wgate, const float* __restrict__ bgate,
    float* __restrict__ lrv, float* __restrict__ momv,
    float* __restrict__ decv, float* __restrict__ og) {
  __shared__ float red[256];
  int n = blockIdx.x, t = threadIdx.x;
  float s0 = 0.f, s1 = 0.f, s2 = 0.f, s3 = 0.f;
  for (int d = t; d < 2048; d += 256) {
    float xv = x[(size_t)n * 2048 + d];
    s0 += xv * wlr[d]; s1 += xv * wmom[d]; s2 += xv * wdec[d]; s3 += xv * wgate[d];
  }
  float r0 = block_reduce_sum(s0, red);
  float r1 = block_reduce_sum(s1, red);
  float r2 = block_reduce_sum(s2, red);
  float r3 = block_reduce_sum(s3, red);
  if (t == 0) {
    lrv[n] = sigmoid_f(r0 + blr[0]);
    momv[n] = sigmoid_f(r1 + bmom[0]);
    decv[n] = sigmoid_f(r2 + bdec[0]);
    og[n] = sigmoid_f(r3 + bgate[0]);
  }
}

__global__ void chunk_means_k(const float* __restrict__ lrv, const float* __restrict__ momv,
                              const float* __restrict__ decv, float* __restrict__ cp) {
  int c = blockIdx.x, t = threadIdx.x;  // 64 threads
  int n = ((t >> 5) << 10) + c * 32 + (t & 31);
  float a = lrv[n], b = momv[n], d = decv[n];
  for (int off = 32; off > 0; off >>= 1) {
    a += __shfl_down(a, off);
    b += __shfl_down(b, off);
    d += __shfl_down(d, off);
  }
  if (t == 0) {
    cp[c * 3 + 0] = a * (1.f / 64.f);
    cp[c * 3 + 1] = b * (1.f / 64.f);
    cp[c * 3 + 2] = d * (1.f / 64.f);
  }
}

__global__ __launch_bounds__(256) void sampnorm2_k(const us* __restrict__ kp_b,
                                                   const float* __restrict__ dh,
                                                   const us* __restrict__ hab,
                                                   const us* __restrict__ pr,
                                                   float* __restrict__ w0inv,
                                                   float* __restrict__ w1inv, int c) {
  __shared__ float red[256];
  int i = blockIdx.x, t = threadIdx.x;
  int row = c * 64 + i;
  float sk = 0.f, sr = 0.f, sdh = 0.f, sa = 0.f;
  for (int p = t; p < 1024; p += 256) {
    float v = bf2f(kp_b[(size_t)row * 1024 + p]); sk += v * v;
    v = bf2f(pr[(size_t)(64 + i) * 1024 + p]); sr += v * v;
  }
  for (int h = t; h < 2048; h += 256) {
    float v = dh[(size_t)i * 2048 + h]; sdh += v * v;
    v = bf2f(hab[(size_t)(64 + i) * 2048 + h]); sa += v * v;
  }
  float tk = block_reduce_sum(sk, red);
  float tdh = block_reduce_sum(sdh, red);
  float ta = block_reduce_sum(sa, red);
  float tr = block_reduce_sum(sr, red);
  if (t == 0) {
    float n0 = fmaxf(sqrtf(tk) * sqrtf(tdh), 1e-8f);
    w0inv[i] = 1.0f / (64.0f * fmaxf(n0 * 0.1f, 1.0f));
    float n1 = fmaxf(sqrtf(ta) * sqrtf(tr), 1e-8f);
    w1inv[i] = 1.0f / (64.0f * fmaxf(n1 * 0.1f, 1.0f));
  }
}

template<int INF32>
__global__ void wtrans_k(const void* __restrict__ in, const float* __restrict__ w,
                         us* __restrict__ out, int C, int ldin) {
  __shared__ float tile[32][33];
  int c0 = blockIdx.x * 32, r0 = blockIdx.y * 32;
  int tx = threadIdx.x, ty = threadIdx.y;
#pragma unroll
  for (int j = 0; j < 4; ++j) {
    int r = r0 + ty + 8 * j, cc = c0 + tx;
    float v;
    if constexpr (INF32) v = ((const float*)in)[(size_t)r * ldin + cc];
    else v = bf2f(((const us*)in)[(size_t)r * ldin + cc]);
    tile[ty + 8 * j][tx] = v * w[r];
  }
  __syncthreads();
#pragma unroll
  for (int j = 0; j < 4; ++j)
    out[(size_t)(c0 + ty + 8 * j) * 64 + r0 + tx] = f2bf(tile[tx][ty + 8 * j]);
}

__global__ __launch_bounds__(256) void frob2_k(const float* __restrict__ s0,
                                               const float* __restrict__ s1, int n,
                                               float* __restrict__ parts) {
  __shared__ float red[256];
  const float* s = blockIdx.z ? s1 : s0;
  float acc = 0.f;
  for (int i = blockIdx.x * 256 + threadIdx.x; i < n; i += gridDim.x * 256) {
    float v = s[i]; acc += v * v;
  }
  float r = block_reduce_sum(acc, red);
  if (threadIdx.x == 0) parts[blockIdx.z * 256 + blockIdx.x] = r;
}

__global__ __launch_bounds__(256) void frob_fin2_k(const float* __restrict__ parts,
                                                   float* __restrict__ inv) {
  __shared__ float red[256];
  float r = block_reduce_sum(parts[blockIdx.x * 256 + threadIdx.x], red);
  if (threadIdx.x == 0) inv[blockIdx.x] = 1.0f / (sqrtf(r) + 1e-7f);
}

__global__ void wupd0_k(float* __restrict__ W0, const us* __restrict__ X,
                        us* __restrict__ W0bT, const float* __restrict__ cp, int c) {
  __shared__ float tl[32][33];
  float lr = cp[c * 3 + 0], om = 1.0f - cp[c * 3 + 2];
  int c0 = blockIdx.x * 32, r0 = blockIdx.y * 32;
  int tx = threadIdx.x, ty = threadIdx.y;
#pragma unroll
  for (int j = 0; j < 4; ++j) {
    int r = r0 + ty + 8 * j, h = c0 + tx;
    size_t idx = (size_t)r * 2048 + h;
    float v = om * W0[idx] + lr * bf2f(X[idx]);
    W0[idx] = v;
    tl[ty + 8 * j][tx] = v;
  }
  __syncthreads();
#pragma unroll
  for (int j = 0; j < 4; ++j)
    W0bT[(size_t)(c0 + ty + 8 * j) * 1024 + r0 + tx] = f2bf(tl[tx][ty + 8 * j]);
}

__global__ void wupd1_k(float* __restrict__ W1, const us* __restrict__ X2,
                        us* __restrict__ W1b, us* __restrict__ W1bT,
                        const float* __restrict__ cp, int c) {
  __shared__ float tX[32][33];
  __shared__ float t2[32][33];
  float lr = cp[c * 3 + 0], om = 1.0f - cp[c * 3 + 2];
  int h0 = blockIdx.x * 32, p0 = blockIdx.y * 32;
  int tx = threadIdx.x, ty = threadIdx.y;
#pragma unroll
  for (int j = 0; j < 4; ++j)
    tX[ty + 8 * j][tx] = bf2f(X2[(size_t)(p0 + ty + 8 * j) * 2048 + h0 + tx]);
  __syncthreads();
#pragma unroll
  for (int j = 0; j < 4; ++j) {
    int h = h0 + ty + 8 * j, p = p0 + tx;
    size_t idx = (size_t)h * 1024 + p;
    float v = om * W1[idx] + lr * tX[tx][ty + 8 * j];
    W1[idx] = v;
    W1b[idx] = f2bf(v);
    t2[tx][ty + 8 * j] = v;
  }
  __syncthreads();
#pragma unroll
  for (int j = 0; j < 4; ++j)
    W1bT[(size_t)(p0 + ty + 8 * j) * 2048 + h0 + tx] = f2bf(t2[ty + 8 * j][tx]);
}

// ---------------- host ----------------

extern "C" void kernel_launch(void* const* d_in, const int* in_sizes, int n_in,
                              void* d_out, int out_size, void* d_ws, size_t ws_size,
                              hipStream_t stream) {
  const float* x = (const float*)d_in[0];
  const float* Wk = (const float*)d_in[1];
  const float* Wv = (const float*)d_in[2];
  const float* Wq = (const float*)d_in[3];
  const float* Wout = (const float*)d_in[4];
  const float* w_lr = (const float*)d_in[5];
  const float* b_lr = (const float*)d_in[6];
  const float* w_mom = (const float*)d_in[7];
  const float* b_mom = (const float*)d_in[8];
  const float* w_dec = (const float*)d_in[9];
  const float* b_dec = (const float*)d_in[10];
  const float* w_gate = (const float*)d_in[11];
  const float* b_gate = (const float*)d_in[12];
  const float* Wmem0 = (const float*)d_in[13];
  const float* Wmem1 = (const float*)d_in[14];
  const float* Wmemout = (const float*)d_in[15];
  const float* Wvexp = (const float*)d_in[16];
  float* out = (float*)d_out;
  (void)n_in; (void)in_sizes; (void)out_size;

  const long F = 1048576;
  const long BIG = 2097152;
  const long SB2 = 2097152, SB1 = 1048576;
  float* ws = (float*)d_ws;
  if (ws_size < (size_t)25043464 * sizeof(float)) return;

  us* kp_b   = (us*)ws;               // [0,1F)
  us* qp_b   = (us*)(ws + F);         // [1,2)
  float* vexp = ws + 2 * F;           // [2,4)
  float* W0  = ws + 4 * F;            // [4,6)
  float* W1  = ws + 6 * F;            // [6,8)
  float* S0  = ws + 8 * F;            // [8,10)
  float* S1  = ws + 10 * F;           // [10,12)
  us* XA     = (us*)(ws + 12 * F);    // [12,14) Xc/Xn row-major [2][1024][2048]
  us* XB     = (us*)(ws + 14 * F);    // [14,16)
  us* XP     = (us*)(ws + 16 * F);    // [16,18) packed X [2] (prologue: vlin/WvexpT)
  us* AP     = (us*)(ws + 18 * F);    // [18,19) packed Ab [2] (final: Woutb)
  float* SCR = ws + 19 * F;           // [19,20) chunk scratch
  us* XTP    = (us*)(ws + 20 * F);    // [20,22) packed XT [2] (= W0bT/W1bT region)
  us* BP     = (us*)(ws + 22 * F);    // [22,23) packed Bb [2] (= W1b region)
  us* W0bT   = (us*)(ws + 20 * F);    // chunk-path alias (regenerated by wupd0)
  us* W1bT   = (us*)(ws + 21 * F);
  us* W1b    = (us*)(ws + 22 * F);
  us* WmoT   = (us*)(ws + 23 * F);    // [23,23.25)
  us* retrv  = (us*)(ws + 23 * F + 262144);
  float* smal = ws + 23 * F + 262144 + 524288;
  float* og   = smal;
  float* lrv  = og + 2048;
  float* momv = lrv + 2048;
  float* decv = momv + 2048;
  float* cpb  = decv + 2048;
  float* w0inv = cpb + 128;
  float* w1inv = w0inv + 64;
  float* parts = w1inv + 64;
  float* inv01 = parts + 512;

  us* xb   = XA;                       // prologue aliases
  us* Wkb  = XB;
  us* Wqb  = XB + 1048576;
  us* Wvb  = XB + 2097152;
  us* vlin = XP;
  us* WvexpT = XP + 1048576;
  us* Woutb = AP;
  float* lin = SCR;
  us* hab   = (us*)SCR;
  float* gp = SCR + 131072;
  us* pr    = (us*)(SCR + 262144);
  float* dh = SCR + 327680;
  us* dhT   = (us*)(SCR + 458752);
  us* rbwT  = (us*)(SCR + 524288);

  const float NSa = 3.4445f, NSb = -4.7750f, NSc = 2.0315f;

  hipMemcpyAsync(W0, Wmem0, (size_t)BIG * 4, hipMemcpyDeviceToDevice, stream);
  hipMemcpyAsync(W1, Wmem1, (size_t)BIG * 4, hipMemcpyDeviceToDevice, stream);
  hipMemsetAsync(S0, 0, (size_t)BIG * 4, stream);
  hipMemsetAsync(S1, 0, (size_t)BIG * 4, stream);
  hipLaunchKernelGGL(tconv_k, dim3(64, 32), dim3(32, 8), 0, stream, Wmem0, W0bT, 1024, 2048);
  hipLaunchKernelGGL(conv_k, dim3(1024), dim3(256), 0, stream, Wmem1, W1b, (int)BIG);
  hipLaunchKernelGGL(tconv_k, dim3(32, 64), dim3(32, 8), 0, stream, Wmem1, W1bT, 2048, 1024);
  hipLaunchKernelGGL(tconv_k, dim3(16, 32), dim3(32, 8), 0, stream, Wmemout, WmoT, 1024, 512);
  hipLaunchKernelGGL(tconv_k, dim3(32, 16), dim3(32, 8), 0, stream, Wvexp, WvexpT, 512, 1024);
  hipLaunchKernelGGL(conv_k, dim3(2048), dim3(256), 0, stream, x, xb, 2048 * 2048);
  hipLaunchKernelGGL(conv_k, dim3(512), dim3(256), 0, stream, Wk, Wkb, 512 * 2048);
  hipLaunchKernelGGL(conv_k, dim3(512), dim3(256), 0, stream, Wq, Wqb, 512 * 2048);
  hipLaunchKernelGGL(conv_k, dim3(512), dim3(256), 0, stream, Wv, Wvb, 512 * 2048);

  mg<7>(stream, xb, nullptr, Wkb, lin, nullptr, nullptr, nullptr, nullptr, nullptr, 0,
        2048, 512, 2048, 2048, 2048, 512, 0);
  hipLaunchKernelGGL(polynorm2_k, dim3(2048), dim3(256), 0, stream, lin, kp_b);
  mg<7>(stream, xb, nullptr, Wqb, lin, nullptr, nullptr, nullptr, nullptr, nullptr, 0,
        2048, 512, 2048, 2048, 2048, 512, 0);
  hipLaunchKernelGGL(polynorm2_k, dim3(2048), dim3(256), 0, stream, lin, qp_b);
  mg<5>(stream, xb, nullptr, Wvb, vlin, nullptr, nullptr, nullptr, nullptr, nullptr, 0,
        2048, 512, 2048, 2048, 2048, 512, 0);
  mg<17>(stream, vlin, nullptr, WvexpT, vexp, nullptr, nullptr, nullptr, nullptr, nullptr, 0,
         2048, 1024, 512, 512, 512, 1024, 0);

  hipLaunchKernelGGL(gates_k, dim3(2048), dim3(256), 0, stream, x,
                     w_lr, b_lr, w_mom, b_mom, w_dec, b_dec, w_gate, b_gate,
                     lrv, momv, decv, og);
  hipLaunchKernelGGL(chunk_means_k, dim3(32), dim3(64), 0, stream, lrv, momv, decv, cpb);

  for (int c = 0; c < 32; ++c) {
    const us* kp_c = kp_b + (size_t)c * 64 * 1024;
    const us* qp_c = qp_b + (size_t)c * 64 * 1024;
    const float* vexp_c = vexp + (size_t)c * 64 * 1024;
    mg<8, 0, 1>(stream, qp_c, kp_c, W0bT, hab, gp, nullptr, nullptr, nullptr, nullptr, 0,
                128, 2048, 1024, 1024, 1024, 2048, 0);
    mg<9>(stream, hab, nullptr, W1bT, pr, nullptr, vexp_c, nullptr, nullptr, nullptr, 0,
          128, 1024, 2048, 2048, 2048, 1024, 1024);
    mg<5>(stream, pr, nullptr, WmoT, retrv + (size_t)c * 64 * 512, nullptr, nullptr,
          nullptr, nullptr, nullptr, 0, 64, 512, 1024, 1024, 1024, 512, 0);
    mg<13>(stream, pr + 64 * 1024, nullptr, W1b, dh, nullptr, gp, nullptr, nullptr, nullptr, 0,
           64, 2048, 1024, 1024, 1024, 2048, 2048);
    hipLaunchKernelGGL(sampnorm2_k, dim3(64), dim3(256), 0, stream,
                       kp_b, dh, hab, pr, w0inv, w1inv, c);
    hipLaunchKernelGGL((wtrans_k<1>), dim3(64, 2), dim3(32, 8), 0, stream, dh, w0inv, dhT, 2048, 2048);
    hipLaunchKernelGGL((wtrans_k<0>), dim3(32, 2), dim3(32, 8), 0, stream, pr + 64 * 1024, w1inv,
                       rbwT, 1024, 1024);
    mg<14, 1>(stream, kp_c, nullptr, dhT, S0, nullptr, nullptr, nullptr, nullptr, cpb, c,
              1024, 2048, 64, 1024, 64, 2048, 0);
    mg<14, 1>(stream, hab + 64 * 2048, nullptr, rbwT, S1, nullptr, nullptr, nullptr, nullptr, cpb, c,
              2048, 1024, 64, 2048, 64, 1024, 0);

    // ---- batched NS5: batch0 = S0 (1024x2048), batch1 = S1^T ----
    hipLaunchKernelGGL(frob2_k, dim3(256, 1, 2), dim3(256), 0, stream, S0, S1, (int)BIG, parts);
    hipLaunchKernelGGL(frob_fin2_k, dim3(2), dim3(256), 0, stream, parts, inv01);
    hipLaunchKernelGGL((scalepk_k<0>), dim3(64, 32), dim3(32, 8), 0, stream,
                       S0, inv01, XA, XP, XTP, 1024, 2048);
    hipLaunchKernelGGL((scalepk_k<1>), dim3(32, 64), dim3(32, 8), 0, stream,
                       S1, inv01 + 1, XA + SB2, XP + SB2, XTP + SB2, 2048, 1024);

    us* Xc = XA;
    us* Xn = XB;
    for (int it = 0; it < 5; ++it) {
      // AP = pack(Xc @ Xc^T)
      mgf<20>(stream, XP, XP, AP, nullptr, 1024, 1024, 2048, 0,
              0.f, 0.f, SB2, SB2, SB1, 0);
      // BP = pack(NSc*(Ab@Ab) + NSb*Ab)
      mgf<21>(stream, AP, AP, BP, AP, 1024, 1024, 1024, 0,
              NSc, NSb, SB1, SB1, SB1, SB1);
      // Xn = Bb@Xc + NSa*Xc (row-major)
      mgf<6>(stream, BP, XTP, Xn, Xc, 1024, 2048, 1024, 2048,
             1.0f, NSa, SB1, SB2, SB2, SB2);
      if (it < 4)
        hipLaunchKernelGGL(packX_k, dim3(64, 32, 2), dim3(32, 8), 0, stream, Xn, XP, XTP);
      us* tmp = Xc; Xc = Xn; Xn = tmp;
    }
    hipLaunchKernelGGL(wupd0_k, dim3(64, 32), dim3(32, 8), 0, stream, W0, Xc, W0bT, cpb, c);
    hipLaunchKernelGGL(wupd1_k, dim3(64, 32), dim3(32, 8), 0, stream, W1, Xc + SB2, W1b, W1bT, cpb, c);
  }

  hipLaunchKernelGGL(conv_k, dim3(1024), dim3(256), 0, stream, Wout, Woutb, 2048 * 512);
  mg<15, 0, 0, 1>(stream, retrv, nullptr, Woutb, out, nullptr, nullptr, x, og, nullptr, 0,
                  2048, 2048, 512, 512, 512, 2048, 0);
}